// Round 1
// baseline (514.392 us; speedup 1.0000x reference)
//
#include <hip/hip_runtime.h>
#include <hip/hip_bf16.h>
#include <stdint.h>
#include <type_traits>

typedef __attribute__((ext_vector_type(8))) short short8;
typedef __attribute__((ext_vector_type(4))) float f32x4;

#define DEV static __device__ __forceinline__

DEV short bf16b(float f) {
  return __builtin_bit_cast(short, __float2bfloat16(f));
}

// ---------------- GEMM: C[m][n] = sum_k A[m][k] * W[n][k] + bias[n] ----------------
// A: fp32 or bf16(short). W: fp32 [N][K]. C: bf16(short) or fp32.
// BM=BN=128, BK=32, 256 threads, 4 waves in 2x2, each wave 64x64 (4x4 frags).
template<typename AT, typename OT>
__global__ __launch_bounds__(256)
void gemm_bt_kernel(const AT* __restrict__ A, const float* __restrict__ W,
                    const float* __restrict__ bias, OT* __restrict__ C,
                    int M, int N, int K)
{
  __shared__ __align__(16) short As[128*32];
  __shared__ __align__(16) short Bs[128*32];
  const int t = threadIdx.x;
  const int lane = t & 63;
  const int wv = t >> 6;
  const int wr = wv >> 1, wc = wv & 1;
  const int l15 = lane & 15, lg = lane >> 4;
  const int m0 = blockIdx.x * 128;
  const int n0 = blockIdx.y * 128;

  f32x4 acc[4][4] = {};

  for (int k0 = 0; k0 < K; k0 += 32) {
    #pragma unroll
    for (int c = 0; c < 2; ++c) {
      const int e = t + c*256;
      const int row = e >> 2;          // 0..127
      const int col = (e & 3) * 8;     // 0,8,16,24
      // XOR swizzle: rows are 64B; xor 16B-slot index with row bits 1-2
      const int byte = row*64 + ((col*2) ^ ((row&6)<<3));
      short8 va;
      if constexpr (std::is_same<AT,float>::value) {
        const float* src = A + (size_t)(m0+row)*K + k0 + col;
        f32x4 f0 = *(const f32x4*)src;
        f32x4 f1 = *(const f32x4*)(src+4);
        #pragma unroll
        for (int j=0;j<4;++j){ va[j]=bf16b(f0[j]); va[4+j]=bf16b(f1[j]); }
      } else {
        va = *(const short8*)(A + (size_t)(m0+row)*K + k0 + col);
      }
      *(short8*)((char*)As + byte) = va;
      const float* srcB = W + (size_t)(n0+row)*K + k0 + col;
      f32x4 g0 = *(const f32x4*)srcB;
      f32x4 g1 = *(const f32x4*)(srcB+4);
      short8 vb;
      #pragma unroll
      for (int j=0;j<4;++j){ vb[j]=bf16b(g0[j]); vb[4+j]=bf16b(g1[j]); }
      *(short8*)((char*)Bs + byte) = vb;
    }
    __syncthreads();
    short8 af[4], bfr[4];
    #pragma unroll
    for (int m=0;m<4;++m) {
      const int row = wr*64 + m*16 + l15;
      af[m] = *(const short8*)((const char*)As + row*64 + ((lg*16) ^ ((row&6)<<3)));
    }
    #pragma unroll
    for (int n=0;n<4;++n) {
      const int row = wc*64 + n*16 + l15;
      bfr[n] = *(const short8*)((const char*)Bs + row*64 + ((lg*16) ^ ((row&6)<<3)));
    }
    #pragma unroll
    for (int m=0;m<4;++m)
      #pragma unroll
      for (int n=0;n<4;++n)
        acc[m][n] = __builtin_amdgcn_mfma_f32_16x16x32_bf16(af[m], bfr[n], acc[m][n], 0, 0, 0);
    __syncthreads();
  }

  #pragma unroll
  for (int n=0;n<4;++n) {
    const int col = n0 + wc*64 + n*16 + l15;
    const float bv = bias[col];
    #pragma unroll
    for (int m=0;m<4;++m) {
      #pragma unroll
      for (int i=0;i<4;++i) {
        const int row = m0 + wr*64 + m*16 + lg*4 + i;
        const float val = acc[m][n][i] + bv;
        if constexpr (std::is_same<OT,float>::value) C[(size_t)row*N + col] = val;
        else                                         C[(size_t)row*N + col] = bf16b(val);
      }
    }
  }
}

// ---------------- V transpose: Vh[b*4096+s][h*64+dk] -> Vt[(b*16+h)*64+dk][s] ----
__global__ __launch_bounds__(256)
void transpose_v_kernel(const short* __restrict__ Vh, short* __restrict__ Vt)
{
  __shared__ short tile[64][65];
  const int t = threadIdx.x;
  const int bh = blockIdx.y, b = bh >> 4, h = bh & 15;
  const int s0 = blockIdx.x * 64;
  const int r = t >> 2;            // 0..63
  const int c = (t & 3) * 16;      // 0,16,32,48
  const short* src = Vh + (size_t)(b*4096 + s0 + r)*1024 + h*64 + c;
  short8 v0 = *(const short8*)src;
  short8 v1 = *(const short8*)(src + 8);
  #pragma unroll
  for (int j=0;j<8;++j){ tile[r][c+j]=v0[j]; tile[r][c+8+j]=v1[j]; }
  __syncthreads();
  short8 o0, o1;
  #pragma unroll
  for (int j=0;j<8;++j){ o0[j]=tile[c+j][r]; o1[j]=tile[c+8+j][r]; }
  short* dst = Vt + (size_t)(bh*64 + r)*4096 + s0 + c;
  *(short8*)dst = o0;
  *(short8*)(dst+8) = o1;
}

// ---------------- Flash attention ----------------
// Grid (32 q-blocks, 32 bh). 256 thr = 4 waves; wave owns 32 q-rows.
// KBLK=64. Ks/Vs XOR-swizzled (128B rows). P via per-wave swizzled LDS.
__global__ __launch_bounds__(256)
void flash_kernel(const short* __restrict__ Qh, const short* __restrict__ Kh,
                  const short* __restrict__ Vt, const int* __restrict__ mask,
                  short* __restrict__ O)
{
  __shared__ __align__(16) short Ks[64*64];
  __shared__ __align__(16) short Vs[64*64];
  __shared__ __align__(16) short Ps[4][32*64];
  __shared__ float Msk[4096];

  const int t = threadIdx.x;
  const int lane = t & 63, wv = t >> 6;
  const int l15 = lane & 15, lg = lane >> 4;
  const int bh = blockIdx.y, b = bh >> 4, h = bh & 15;
  const int q0 = blockIdx.x * 128;

  for (int i = t; i < 4096; i += 256)
    Msk[i] = (mask[b*4096 + i] == 0) ? -1e9f : 0.0f;

  short8 qf[2][2];
  #pragma unroll
  for (int m=0;m<2;++m)
    #pragma unroll
    for (int kk=0;kk<2;++kk)
      qf[m][kk] = *(const short8*)(Qh + (size_t)(b*4096 + q0 + wv*32 + m*16 + l15)*1024
                                   + h*64 + kk*32 + lg*8);

  float m_run[2][4], l_part[2][4];
  f32x4 o_acc[2][4];
  #pragma unroll
  for (int m=0;m<2;++m)
    #pragma unroll
    for (int i=0;i<4;++i){ m_run[m][i]=-3e38f; l_part[m][i]=0.f; }
  #pragma unroll
  for (int m=0;m<2;++m)
    #pragma unroll
    for (int c=0;c<4;++c) o_acc[m][c] = (f32x4){0.f,0.f,0.f,0.f};

  for (int kt = 0; kt < 64; ++kt) {
    #pragma unroll
    for (int c = 0; c < 2; ++c) {
      const int e = t + c*256;
      const int row = e >> 3;            // 0..63
      const int colb = (e & 7) * 16;     // byte col
      const int byte = row*128 + (colb ^ ((row&7)<<4));
      *(short8*)((char*)Ks + byte) =
        *(const short8*)(Kh + (size_t)(b*4096 + kt*64 + row)*1024 + h*64 + (colb>>1));
      *(short8*)((char*)Vs + byte) =
        *(const short8*)(Vt + (size_t)(bh*64 + row)*4096 + kt*64 + (colb>>1));
    }
    __syncthreads();

    // ---- S = Q K^T ----
    f32x4 s_acc[2][4] = {};
    short8 kf[4][2];
    #pragma unroll
    for (int n=0;n<4;++n) {
      const int row = n*16 + l15;
      #pragma unroll
      for (int kk=0;kk<2;++kk)
        kf[n][kk] = *(const short8*)((const char*)Ks + row*128
                                     + ((kk*64 + lg*16) ^ ((row&7)<<4)));
    }
    #pragma unroll
    for (int kk=0;kk<2;++kk)
      #pragma unroll
      for (int m=0;m<2;++m)
        #pragma unroll
        for (int n=0;n<4;++n)
          s_acc[m][n] = __builtin_amdgcn_mfma_f32_16x16x32_bf16(qf[m][kk], kf[n][kk], s_acc[m][n], 0,0,0);

    float mk[4];
    #pragma unroll
    for (int n=0;n<4;++n) mk[n] = Msk[kt*64 + n*16 + l15];

    // ---- online softmax (rows = lg*4+i within each 16-row frag) ----
    #pragma unroll
    for (int m=0;m<2;++m) {
      #pragma unroll
      for (int i=0;i<4;++i) {
        float sv[4];
        #pragma unroll
        for (int n=0;n<4;++n) sv[n] = s_acc[m][n][i]*0.125f + mk[n];
        float mx = fmaxf(fmaxf(sv[0],sv[1]), fmaxf(sv[2],sv[3]));
        #pragma unroll
        for (int d=1; d<16; d<<=1) mx = fmaxf(mx, __shfl_xor(mx, d, 64));
        mx = fmaxf(mx, m_run[m][i]);
        const float sc = __expf(m_run[m][i] - mx);
        m_run[m][i] = mx;
        l_part[m][i] *= sc;
        #pragma unroll
        for (int c=0;c<4;++c) o_acc[m][c][i] *= sc;
        const int row = m*16 + lg*4 + i;
        #pragma unroll
        for (int n=0;n<4;++n) {
          const float p = __expf(sv[n] - mx);
          l_part[m][i] += p;
          const int col = n*16 + l15;
          const int byte = row*128 + ((((col>>3)<<4) ^ ((row&7)<<4))) + (col&7)*2;
          *(short*)((char*)&Ps[wv][0] + byte) = bf16b(p);
        }
      }
    }
    // P writes are cross-lane consumed by the same wave: drain LDS, pin order.
    asm volatile("s_waitcnt lgkmcnt(0)" ::: "memory");
    __builtin_amdgcn_sched_barrier(0);

    // ---- O += P V ----
    short8 pf[2][2], vf[4][2];
    #pragma unroll
    for (int m=0;m<2;++m) {
      const int row = m*16 + l15;
      #pragma unroll
      for (int kk=0;kk<2;++kk)
        pf[m][kk] = *(const short8*)((const char*)&Ps[wv][0] + row*128
                                     + ((kk*64 + lg*16) ^ ((row&7)<<4)));
    }
    #pragma unroll
    for (int c=0;c<4;++c) {
      const int row = c*16 + l15;
      #pragma unroll
      for (int kk=0;kk<2;++kk)
        vf[c][kk] = *(const short8*)((const char*)Vs + row*128
                                     + ((kk*64 + lg*16) ^ ((row&7)<<4)));
    }
    #pragma unroll
    for (int kk=0;kk<2;++kk)
      #pragma unroll
      for (int m=0;m<2;++m)
        #pragma unroll
        for (int c=0;c<4;++c)
          o_acc[m][c] = __builtin_amdgcn_mfma_f32_16x16x32_bf16(pf[m][kk], vf[c][kk], o_acc[m][c], 0,0,0);
    __syncthreads();
  }

  // ---- epilogue: reduce row sums across the 16-lane groups, normalize, store ----
  #pragma unroll
  for (int m=0;m<2;++m) {
    #pragma unroll
    for (int i=0;i<4;++i) {
      float lr = l_part[m][i];
      #pragma unroll
      for (int d=1; d<16; d<<=1) lr += __shfl_xor(lr, d, 64);
      const float inv = 1.0f / lr;
      const int row = b*4096 + q0 + wv*32 + m*16 + lg*4 + i;
      #pragma unroll
      for (int c=0;c<4;++c)
        O[(size_t)row*1024 + h*64 + c*16 + l15] = bf16b(o_acc[m][c][i] * inv);
    }
  }
}

extern "C" void kernel_launch(void* const* d_in, const int* in_sizes, int n_in,
                              void* d_out, int out_size, void* d_ws, size_t ws_size,
                              hipStream_t stream)
{
  const float* q    = (const float*)d_in[0];
  const float* k    = (const float*)d_in[1];
  const float* v    = (const float*)d_in[2];
  const int*   mask = (const int*)d_in[3];
  const float* w_q  = (const float*)d_in[4];
  const float* b_q  = (const float*)d_in[5];
  const float* w_k  = (const float*)d_in[6];
  const float* b_k  = (const float*)d_in[7];
  const float* w_v  = (const float*)d_in[8];
  const float* b_v  = (const float*)d_in[9];
  const float* w_o  = (const float*)d_in[10];
  const float* b_o  = (const float*)d_in[11];
  float* out = (float*)d_out;

  char* ws = (char*)d_ws;
  const size_t SZ = (size_t)8192*1024*2;   // one bf16 [8192][1024] buffer
  short* QH = (short*)(ws);
  short* KH = (short*)(ws + SZ);
  short* OB = (short*)(ws + 2*SZ);         // V-proj output, then reused for attn out
  short* VT = (short*)(ws + 3*SZ);
  short* VH = OB;

  dim3 bG(256);
  dim3 gG(64, 8);
  hipLaunchKernelGGL((gemm_bt_kernel<float, short>), gG, bG, 0, stream, q, w_q, b_q, QH, 8192, 1024, 1024);
  hipLaunchKernelGGL((gemm_bt_kernel<float, short>), gG, bG, 0, stream, k, w_k, b_k, KH, 8192, 1024, 1024);
  hipLaunchKernelGGL((gemm_bt_kernel<float, short>), gG, bG, 0, stream, v, w_v, b_v, VH, 8192, 1024, 1024);
  hipLaunchKernelGGL(transpose_v_kernel, dim3(64, 32), bG, 0, stream, VH, VT);
  hipLaunchKernelGGL(flash_kernel, dim3(32, 32), bG, 0, stream, QH, KH, VT, mask, OB);
  hipLaunchKernelGGL((gemm_bt_kernel<short, float>), gG, bG, 0, stream, OB, w_o, b_o, out, 8192, 1024, 1024);
}

// Round 3
// 433.458 us; speedup vs baseline: 1.1867x; 1.1867x over previous
//
#include <hip/hip_runtime.h>
#include <hip/hip_bf16.h>
#include <stdint.h>
#include <type_traits>

typedef __attribute__((ext_vector_type(8))) short short8;
typedef __attribute__((ext_vector_type(4))) float f32x4;
typedef __attribute__((ext_vector_type(16))) float f32x16;
typedef __attribute__((ext_vector_type(4))) int i32x4;
typedef __attribute__((ext_vector_type(4))) unsigned int uint4v;

#define DEV static __device__ __forceinline__

DEV short bf16b(float f) {
  return __builtin_bit_cast(short, __float2bfloat16(f));
}
DEV float exp2a(float x){ float r; asm("v_exp_f32 %0, %1" : "=v"(r) : "v"(x)); return r; }
DEV unsigned cvtpk(float lo, float hi){ unsigned r; asm("v_cvt_pk_bf16_f32 %0, %1, %2" : "=v"(r) : "v"(lo), "v"(hi)); return r; }

// ---------------- GEMM: C[m][n] = (sum_k A[m][k] * W[n][k] + bias[n]) * oscale ----
template<typename AT, typename OT>
__global__ __launch_bounds__(256)
void gemm_bt_kernel(const AT* __restrict__ A, const float* __restrict__ W,
                    const float* __restrict__ bias, OT* __restrict__ C,
                    int M, int N, int K, float oscale)
{
  __shared__ __align__(16) short As[128*32];
  __shared__ __align__(16) short Bs[128*32];
  const int t = threadIdx.x;
  const int lane = t & 63;
  const int wv = t >> 6;
  const int wr = wv >> 1, wc = wv & 1;
  const int l15 = lane & 15, lg = lane >> 4;
  const int m0 = blockIdx.x * 128;
  const int n0 = blockIdx.y * 128;

  f32x4 acc[4][4] = {};

  for (int k0 = 0; k0 < K; k0 += 32) {
    #pragma unroll
    for (int c = 0; c < 2; ++c) {
      const int e = t + c*256;
      const int row = e >> 2;
      const int col = (e & 3) * 8;
      const int byte = row*64 + ((col*2) ^ ((row&6)<<3));
      short8 va;
      if constexpr (std::is_same<AT,float>::value) {
        const float* src = A + (size_t)(m0+row)*K + k0 + col;
        f32x4 f0 = *(const f32x4*)src;
        f32x4 f1 = *(const f32x4*)(src+4);
        #pragma unroll
        for (int j=0;j<4;++j){ va[j]=bf16b(f0[j]); va[4+j]=bf16b(f1[j]); }
      } else {
        va = *(const short8*)(A + (size_t)(m0+row)*K + k0 + col);
      }
      *(short8*)((char*)As + byte) = va;
      const float* srcB = W + (size_t)(n0+row)*K + k0 + col;
      f32x4 g0 = *(const f32x4*)srcB;
      f32x4 g1 = *(const f32x4*)(srcB+4);
      short8 vb;
      #pragma unroll
      for (int j=0;j<4;++j){ vb[j]=bf16b(g0[j]); vb[4+j]=bf16b(g1[j]); }
      *(short8*)((char*)Bs + byte) = vb;
    }
    __syncthreads();
    short8 af[4], bfr[4];
    #pragma unroll
    for (int m=0;m<4;++m) {
      const int row = wr*64 + m*16 + l15;
      af[m] = *(const short8*)((const char*)As + row*64 + ((lg*16) ^ ((row&6)<<3)));
    }
    #pragma unroll
    for (int n=0;n<4;++n) {
      const int row = wc*64 + n*16 + l15;
      bfr[n] = *(const short8*)((const char*)Bs + row*64 + ((lg*16) ^ ((row&6)<<3)));
    }
    #pragma unroll
    for (int m=0;m<4;++m)
      #pragma unroll
      for (int n=0;n<4;++n)
        acc[m][n] = __builtin_amdgcn_mfma_f32_16x16x32_bf16(af[m], bfr[n], acc[m][n], 0, 0, 0);
    __syncthreads();
  }

  #pragma unroll
  for (int n=0;n<4;++n) {
    const int col = n0 + wc*64 + n*16 + l15;
    const float bv = bias[col];
    #pragma unroll
    for (int m=0;m<4;++m) {
      #pragma unroll
      for (int i=0;i<4;++i) {
        const int row = m0 + wr*64 + m*16 + lg*4 + i;
        const float val = (acc[m][n][i] + bv) * oscale;
        if constexpr (std::is_same<OT,float>::value) C[(size_t)row*N + col] = val;
        else                                         C[(size_t)row*N + col] = bf16b(val);
      }
    }
  }
}

// ---------------- V transpose: Vh[b*4096+s][h*64+dk] -> Vt[(b*16+h)*64+dk][s] ----
__global__ __launch_bounds__(256)
void transpose_v_kernel(const short* __restrict__ Vh, short* __restrict__ Vt)
{
  __shared__ short tile[64][65];
  const int t = threadIdx.x;
  const int bh = blockIdx.y, b = bh >> 4, h = bh & 15;
  const int s0 = blockIdx.x * 64;
  const int r = t >> 2;
  const int c = (t & 3) * 16;
  const short* src = Vh + (size_t)(b*4096 + s0 + r)*1024 + h*64 + c;
  short8 v0 = *(const short8*)src;
  short8 v1 = *(const short8*)(src + 8);
  #pragma unroll
  for (int j=0;j<8;++j){ tile[r][c+j]=v0[j]; tile[r][c+8+j]=v1[j]; }
  __syncthreads();
  short8 o0, o1;
  #pragma unroll
  for (int j=0;j<8;++j){ o0[j]=tile[c+j][r]; o1[j]=tile[c+8+j][r]; }
  short* dst = Vt + (size_t)(bh*64 + r)*4096 + s0 + c;
  *(short8*)dst = o0;
  *(short8*)(dst+8) = o1;
}

// ---------------- Flash attention, swapped-QK 32x32 structure ----------------
// Grid (32 q-blocks, 32 bh). 256 thr = 4 waves; wave owns 32 q-rows.
// Per lane: q = lane&31 for scores, l, m, AND O^T accumulator.
__global__ __launch_bounds__(256)
void flash_kernel(const short* __restrict__ Qh, const short* __restrict__ Kh,
                  const short* __restrict__ Vt, const int* __restrict__ mask,
                  short* __restrict__ O)
{
  __shared__ __align__(16) short Ks[2][64*64];
  __shared__ __align__(16) short Vs[2][64*64];

  const int t = threadIdx.x;
  const int lane = t & 63, wv = t >> 6;
  const int l31 = lane & 31, hi = lane >> 5;
  const int rsw = (l31 & 7) << 4;
  const int bh = blockIdx.y, b = bh >> 4, h = bh & 15;
  const int q0 = blockIdx.x * 128;

  // Q B-frags (already scaled by 0.125*log2e in the Q projection)
  short8 qf[4];
  {
    const short* qrow = Qh + (size_t)(b*4096 + q0 + wv*32 + l31)*1024 + h*64;
    #pragma unroll
    for (int ds=0; ds<4; ++ds)
      qf[ds] = *(const short8*)(qrow + ds*16 + hi*8);
  }
  const int* mrow = mask + (size_t)b*4096;

  float m_run = -3.0e38f;
  float l_run = 0.0f;
  f32x16 oA[2] = {};

  // prologue: stage tile 0
  #pragma unroll
  for (int c = 0; c < 2; ++c) {
    const int e = t + c*256;
    const int row = e >> 3, sl = e & 7;
    const int byte = row*128 + ((sl*16) ^ ((row&7)<<4));
    *(short8*)((char*)Ks[0] + byte) =
      *(const short8*)(Kh + (size_t)(b*4096 + row)*1024 + h*64 + sl*8);
    *(short8*)((char*)Vs[0] + byte) =
      *(const short8*)(Vt + (size_t)(bh*64 + row)*4096 + sl*8);
  }
  __syncthreads();

  for (int kt = 0; kt < 64; ++kt) {
    const int cur = kt & 1;
    const char* KsC = (const char*)Ks[cur];
    const char* VsC = (const char*)Vs[cur];
    const bool more = (kt + 1 < 64);

    // issue next-tile global loads early (latency hides under QK+softmax+PV)
    short8 nk[2], nv[2];
    if (more) {
      #pragma unroll
      for (int c=0;c<2;++c){
        const int e = t + c*256; const int row = e>>3, sl = e&7;
        nk[c] = *(const short8*)(Kh + (size_t)(b*4096 + (kt+1)*64 + row)*1024 + h*64 + sl*8);
        nv[c] = *(const short8*)(Vt + (size_t)(bh*64 + row)*4096 + (kt+1)*64 + sl*8);
      }
    }
    // mask (int -> additive float, log2 domain): k = kh*32 + rq*8 + hi*4 + (0..3)
    f32x4 mq[2][4];
    #pragma unroll
    for (int kh=0;kh<2;++kh)
      #pragma unroll
      for (int rq=0;rq<4;++rq) {
        i32x4 mi = *(const i32x4*)(mrow + kt*64 + kh*32 + rq*8 + hi*4);
        #pragma unroll
        for (int e=0;e<4;++e) mq[kh][rq][e] = (mi[e]==0) ? -1.0e9f : 0.0f;
      }

    // ---- S^T = K Q^T : lane holds q=l31, k over regs ----
    f32x16 sA[2] = {};
    __builtin_amdgcn_s_setprio(1);
    #pragma unroll
    for (int ds=0; ds<4; ++ds) {
      short8 kf0 = *(const short8*)(KsC + l31*128       + ((ds*32 + hi*16) ^ rsw));
      short8 kf1 = *(const short8*)(KsC + (l31+32)*128  + ((ds*32 + hi*16) ^ rsw));
      sA[0] = __builtin_amdgcn_mfma_f32_32x32x16_bf16(kf0, qf[ds], sA[0], 0,0,0);
      sA[1] = __builtin_amdgcn_mfma_f32_32x32x16_bf16(kf1, qf[ds], sA[1], 0,0,0);
    }
    __builtin_amdgcn_s_setprio(0);

    // ---- softmax (in-register, log2 domain) ----
    #pragma unroll
    for (int kh=0;kh<2;++kh)
      #pragma unroll
      for (int r=0;r<16;++r)
        sA[kh][r] += mq[kh][r>>2][r&3];

    float mx[16];
    #pragma unroll
    for (int r=0;r<16;++r) mx[r] = fmaxf(sA[0][r], sA[1][r]);
    #pragma unroll
    for (int s=8; s>0; s>>=1)
      #pragma unroll
      for (int r=0;r<8;++r) if (r < s) mx[r] = fmaxf(mx[r], mx[r+s]);
    float tmx = mx[0];
    tmx = fmaxf(tmx, __shfl_xor(tmx, 32));

    const float mnew = fmaxf(m_run, tmx);
    const float sc = exp2a(m_run - mnew);
    m_run = mnew;
    l_run *= sc;
    #pragma unroll
    for (int n=0;n<2;++n)
      #pragma unroll
      for (int r=0;r<16;++r) oA[n][r] *= sc;

    f32x4 lp = {0.f,0.f,0.f,0.f};
    #pragma unroll
    for (int kh=0;kh<2;++kh)
      #pragma unroll
      for (int r=0;r<16;++r) {
        const float p = exp2a(sA[kh][r] - m_run);
        sA[kh][r] = p;
        lp[r&3] += p;
      }
    l_run += (lp[0]+lp[1]) + (lp[2]+lp[3]);

    // ---- P -> bf16 B-frags (shfl_xor half-exchange, direction-unambiguous) ----
    // target w[tt][w]: lane (q=l31,hi) holds keys (tt*16 + hi*8 + 2w, +1)
    unsigned w[4][4];
    const bool lo = (lane < 32);
    #pragma unroll
    for (int tt=0; tt<4; ++tt) {
      const int kh = tt>>1, ro = (tt&1)*8;
      unsigned c01 = cvtpk(sA[kh][ro+0], sA[kh][ro+1]);  // hi=0: keys(0,1)  hi=1: keys(4,5)   (+tt*16 base)
      unsigned c23 = cvtpk(sA[kh][ro+2], sA[kh][ro+3]);  // (2,3)/(6,7)
      unsigned c45 = cvtpk(sA[kh][ro+4], sA[kh][ro+5]);  // (8,9)/(12,13)
      unsigned c67 = cvtpk(sA[kh][ro+6], sA[kh][ro+7]);  // (10,11)/(14,15)
      unsigned s01 = __shfl_xor(c01, 32);
      unsigned s23 = __shfl_xor(c23, 32);
      unsigned s45 = __shfl_xor(c45, 32);
      unsigned s67 = __shfl_xor(c67, 32);
      w[tt][0] = lo ? c01 : s45;   // keys hi*8+0,1
      w[tt][1] = lo ? c23 : s67;   // keys hi*8+2,3
      w[tt][2] = lo ? s01 : c45;   // keys hi*8+4,5
      w[tt][3] = lo ? s23 : c67;   // keys hi*8+6,7
    }

    // ---- O^T += V^T P^T ----
    __builtin_amdgcn_s_setprio(1);
    #pragma unroll
    for (int n=0;n<2;++n) {
      #pragma unroll
      for (int tt=0;tt<4;++tt) {
        short8 vf = *(const short8*)(VsC + (n*32+l31)*128 + ((tt*32 + hi*16) ^ rsw));
        uint4v wp = {w[tt][0], w[tt][1], w[tt][2], w[tt][3]};
        oA[n] = __builtin_amdgcn_mfma_f32_32x32x16_bf16(vf, __builtin_bit_cast(short8, wp), oA[n], 0,0,0);
      }
    }
    __builtin_amdgcn_s_setprio(0);

    // ---- write next tile into the other buffer ----
    if (more) {
      #pragma unroll
      for (int c=0;c<2;++c){
        const int e = t + c*256; const int row = e>>3, sl = e&7;
        const int byte = row*128 + ((sl*16) ^ ((row&7)<<4));
        *(short8*)((char*)Ks[cur^1] + byte) = nk[c];
        *(short8*)((char*)Vs[cur^1] + byte) = nv[c];
      }
    }
    __syncthreads();
  }

  // ---- epilogue ----
  l_run += __shfl_xor(l_run, 32);
  const float inv = 1.0f / l_run;

  char* ot = (char*)Ks + wv*4096;   // 4KB per wave, reuse K LDS
  #pragma unroll
  for (int n=0;n<2;++n)
    #pragma unroll
    for (int rq=0;rq<4;++rq) {
      const unsigned w0 = cvtpk(oA[n][rq*4+0]*inv, oA[n][rq*4+1]*inv);
      const unsigned w1 = cvtpk(oA[n][rq*4+2]*inv, oA[n][rq*4+3]*inv);
      const int sl = n*4 + rq;
      const int byte = l31*128 + ((sl*16) ^ ((l31&7)<<4)) + hi*8;
      *(unsigned*)(ot + byte)     = w0;
      *(unsigned*)(ot + byte + 4) = w1;
    }
  asm volatile("s_waitcnt lgkmcnt(0)" ::: "memory");
  __builtin_amdgcn_sched_barrier(0);

  const int row = lane >> 1, half = lane & 1;
  const int orow = b*4096 + q0 + wv*32 + row;
  #pragma unroll
  for (int i=0;i<4;++i) {
    const int sl = half*4 + i;
    short8 vv = *(const short8*)(ot + row*128 + ((sl*16) ^ ((row&7)<<4)));
    *(short8*)(O + (size_t)orow*1024 + h*64 + half*32 + i*8) = vv;
  }
}

extern "C" void kernel_launch(void* const* d_in, const int* in_sizes, int n_in,
                              void* d_out, int out_size, void* d_ws, size_t ws_size,
                              hipStream_t stream)
{
  const float* q    = (const float*)d_in[0];
  const float* k    = (const float*)d_in[1];
  const float* v    = (const float*)d_in[2];
  const int*   mask = (const int*)d_in[3];
  const float* w_q  = (const float*)d_in[4];
  const float* b_q  = (const float*)d_in[5];
  const float* w_k  = (const float*)d_in[6];
  const float* b_k  = (const float*)d_in[7];
  const float* w_v  = (const float*)d_in[8];
  const float* b_v  = (const float*)d_in[9];
  const float* w_o  = (const float*)d_in[10];
  const float* b_o  = (const float*)d_in[11];
  float* out = (float*)d_out;

  char* ws = (char*)d_ws;
  const size_t SZ = (size_t)8192*1024*2;   // one bf16 [8192][1024] buffer
  short* QH = (short*)(ws);
  short* KH = (short*)(ws + SZ);
  short* OB = (short*)(ws + 2*SZ);         // V-proj output, then reused for attn out
  short* VT = (short*)(ws + 3*SZ);
  short* VH = OB;

  const float QSCALE = 0.125f * 1.44269504f;

  dim3 bG(256);
  dim3 gG(64, 8);
  hipLaunchKernelGGL((gemm_bt_kernel<float, short>), gG, bG, 0, stream, q, w_q, b_q, QH, 8192, 1024, 1024, QSCALE);
  hipLaunchKernelGGL((gemm_bt_kernel<float, short>), gG, bG, 0, stream, k, w_k, b_k, KH, 8192, 1024, 1024, 1.0f);
  hipLaunchKernelGGL((gemm_bt_kernel<float, short>), gG, bG, 0, stream, v, w_v, b_v, VH, 8192, 1024, 1024, 1.0f);
  hipLaunchKernelGGL(transpose_v_kernel, dim3(64, 32), bG, 0, stream, VH, VT);
  hipLaunchKernelGGL(flash_kernel, dim3(32, 32), bG, 0, stream, QH, KH, VT, mask, OB);
  hipLaunchKernelGGL((gemm_bt_kernel<short, float>), gG, bG, 0, stream, OB, w_o, b_o, out, 8192, 1024, 1024, 1.0f);
}

// Round 5
// 387.779 us; speedup vs baseline: 1.3265x; 1.1178x over previous
//
#include <hip/hip_runtime.h>
#include <hip/hip_bf16.h>
#include <stdint.h>
#include <type_traits>

typedef __attribute__((ext_vector_type(8))) short short8;
typedef __attribute__((ext_vector_type(4))) float f32x4;
typedef __attribute__((ext_vector_type(16))) float f32x16;
typedef __attribute__((ext_vector_type(4))) unsigned int uint4v;

#define DEV static __device__ __forceinline__

DEV short bf16b(float f) {
  return __builtin_bit_cast(short, __float2bfloat16(f));
}
DEV float exp2a(float x){ float r; asm("v_exp_f32 %0, %1" : "=v"(r) : "v"(x)); return r; }
DEV unsigned cvtpk(float lo, float hi){ unsigned r; asm("v_cvt_pk_bf16_f32 %0, %1, %2" : "=v"(r) : "v"(lo), "v"(hi)); return r; }

// ---------------- GEMM: C[m][n] = (sum_k A[m][k] * W[n][k] + bias[n]) * oscale ----
template<typename AT, typename OT>
__global__ __launch_bounds__(256)
void gemm_bt_kernel(const AT* __restrict__ A, const float* __restrict__ W,
                    const float* __restrict__ bias, OT* __restrict__ C,
                    int M, int N, int K, float oscale)
{
  __shared__ __align__(16) short As[128*32];
  __shared__ __align__(16) short Bs[128*32];
  const int t = threadIdx.x;
  const int lane = t & 63;
  const int wv = t >> 6;
  const int wr = wv >> 1, wc = wv & 1;
  const int l15 = lane & 15, lg = lane >> 4;
  const int m0 = blockIdx.x * 128;
  const int n0 = blockIdx.y * 128;

  f32x4 acc[4][4] = {};

  for (int k0 = 0; k0 < K; k0 += 32) {
    #pragma unroll
    for (int c = 0; c < 2; ++c) {
      const int e = t + c*256;
      const int row = e >> 2;
      const int col = (e & 3) * 8;
      const int byte = row*64 + ((col*2) ^ ((row&6)<<3));
      short8 va;
      if constexpr (std::is_same<AT,float>::value) {
        const float* src = A + (size_t)(m0+row)*K + k0 + col;
        f32x4 f0 = *(const f32x4*)src;
        f32x4 f1 = *(const f32x4*)(src+4);
        #pragma unroll
        for (int j=0;j<4;++j){ va[j]=bf16b(f0[j]); va[4+j]=bf16b(f1[j]); }
      } else {
        va = *(const short8*)(A + (size_t)(m0+row)*K + k0 + col);
      }
      *(short8*)((char*)As + byte) = va;
      const float* srcB = W + (size_t)(n0+row)*K + k0 + col;
      f32x4 g0 = *(const f32x4*)srcB;
      f32x4 g1 = *(const f32x4*)(srcB+4);
      short8 vb;
      #pragma unroll
      for (int j=0;j<4;++j){ vb[j]=bf16b(g0[j]); vb[4+j]=bf16b(g1[j]); }
      *(short8*)((char*)Bs + byte) = vb;
    }
    __syncthreads();
    short8 af[4], bfr[4];
    #pragma unroll
    for (int m=0;m<4;++m) {
      const int row = wr*64 + m*16 + l15;
      af[m] = *(const short8*)((const char*)As + row*64 + ((lg*16) ^ ((row&6)<<3)));
    }
    #pragma unroll
    for (int n=0;n<4;++n) {
      const int row = wc*64 + n*16 + l15;
      bfr[n] = *(const short8*)((const char*)Bs + row*64 + ((lg*16) ^ ((row&6)<<3)));
    }
    #pragma unroll
    for (int m=0;m<4;++m)
      #pragma unroll
      for (int n=0;n<4;++n)
        acc[m][n] = __builtin_amdgcn_mfma_f32_16x16x32_bf16(af[m], bfr[n], acc[m][n], 0, 0, 0);
    __syncthreads();
  }

  #pragma unroll
  for (int n=0;n<4;++n) {
    const int col = n0 + wc*64 + n*16 + l15;
    const float bv = bias[col];
    #pragma unroll
    for (int m=0;m<4;++m) {
      #pragma unroll
      for (int i=0;i<4;++i) {
        const int row = m0 + wr*64 + m*16 + lg*4 + i;
        const float val = (acc[m][n][i] + bv) * oscale;
        if constexpr (std::is_same<OT,float>::value) C[(size_t)row*N + col] = val;
        else                                         C[(size_t)row*N + col] = bf16b(val);
      }
    }
  }
}

// ---------------- V transpose: Vh[b*4096+s][h*64+dk] -> Vt[(b*16+h)*64+dk][s] ----
__global__ __launch_bounds__(256)
void transpose_v_kernel(const short* __restrict__ Vh, short* __restrict__ Vt)
{
  __shared__ short tile[64][65];
  const int t = threadIdx.x;
  const int bh = blockIdx.y, b = bh >> 4, h = bh & 15;
  const int s0 = blockIdx.x * 64;
  const int r = t >> 2;
  const int c = (t & 3) * 16;
  const short* src = Vh + (size_t)(b*4096 + s0 + r)*1024 + h*64 + c;
  short8 v0 = *(const short8*)src;
  short8 v1 = *(const short8*)(src + 8);
  #pragma unroll
  for (int j=0;j<8;++j){ tile[r][c+j]=v0[j]; tile[r][c+8+j]=v1[j]; }
  __syncthreads();
  short8 o0, o1;
  #pragma unroll
  for (int j=0;j<8;++j){ o0[j]=tile[c+j][r]; o1[j]=tile[c+8+j][r]; }
  short* dst = Vt + (size_t)(bh*64 + r)*4096 + s0 + c;
  *(short8*)dst = o0;
  *(short8*)(dst+8) = o1;
}

// ---------------- Flash attention, swapped-QK 32x32 structure ----------------
// Grid (32 q-blocks, 32 bh). 256 thr = 4 waves; wave owns 32 q-rows.
// Per lane: q = lane&31 for scores, l, m, AND O^T accumulator.
// Mask enters via the S-accumulator init (additive floats staged in LDS).
// Cross-half exchanges use __shfl_xor (direction-unambiguous; permlane TBD).
__global__ __launch_bounds__(256)
void flash_kernel(const short* __restrict__ Qh, const short* __restrict__ Kh,
                  const short* __restrict__ Vt, const int* __restrict__ mask,
                  short* __restrict__ O)
{
  __shared__ __align__(16) short Ks[2][64*64];
  __shared__ __align__(16) short Vs[2][64*64];
  __shared__ __align__(16) float MaskF[4096];

  const int t = threadIdx.x;
  const int lane = t & 63, wv = t >> 6;
  const int l31 = lane & 31, hi = lane >> 5;
  const int rsw = (l31 & 7) << 4;
  const int bh = blockIdx.y, b = bh >> 4, h = bh & 15;
  const int q0 = blockIdx.x * 128;

  // mask -> additive float (log2 domain), once per block
  for (int i = t; i < 4096; i += 256)
    MaskF[i] = (mask[b*4096 + i] == 0) ? -1.0e9f : 0.0f;

  // Q B-frags (already scaled by 0.125*log2e in the Q projection)
  short8 qf[4];
  {
    const short* qrow = Qh + (size_t)(b*4096 + q0 + wv*32 + l31)*1024 + h*64;
    #pragma unroll
    for (int ds=0; ds<4; ++ds)
      qf[ds] = *(const short8*)(qrow + ds*16 + hi*8);
  }

  float m_run = -3.0e38f;
  float l_run = 0.0f;
  f32x16 oA[2] = {};

  // prologue: stage tile 0
  #pragma unroll
  for (int c = 0; c < 2; ++c) {
    const int e = t + c*256;
    const int row = e >> 3, sl = e & 7;
    const int byte = row*128 + ((sl*16) ^ ((row&7)<<4));
    *(short8*)((char*)Ks[0] + byte) =
      *(const short8*)(Kh + (size_t)(b*4096 + row)*1024 + h*64 + sl*8);
    *(short8*)((char*)Vs[0] + byte) =
      *(const short8*)(Vt + (size_t)(bh*64 + row)*4096 + sl*8);
  }
  __syncthreads();

  for (int kt = 0; kt < 64; ++kt) {
    const int cur = kt & 1;
    const char* KsC = (const char*)Ks[cur];
    const char* VsC = (const char*)Vs[cur];
    const bool more = (kt + 1 < 64);

    // issue next-tile global loads early (latency hides under QK+softmax+PV)
    short8 nk[2], nv[2];
    if (more) {
      #pragma unroll
      for (int c=0;c<2;++c){
        const int e = t + c*256; const int row = e>>3, sl = e&7;
        nk[c] = *(const short8*)(Kh + (size_t)(b*4096 + (kt+1)*64 + row)*1024 + h*64 + sl*8);
        nv[c] = *(const short8*)(Vt + (size_t)(bh*64 + row)*4096 + (kt+1)*64 + sl*8);
      }
    }

    // ---- S accumulator init = additive mask (keys per C-layout: (r&3)+8*(r>>2)+4*hi) ----
    f32x16 sA[2];
    #pragma unroll
    for (int kh=0;kh<2;++kh)
      #pragma unroll
      for (int rq=0;rq<4;++rq) {
        f32x4 mv = *(const f32x4*)(&MaskF[kt*64 + kh*32 + rq*8 + hi*4]);
        sA[kh][rq*4+0] = mv[0]; sA[kh][rq*4+1] = mv[1];
        sA[kh][rq*4+2] = mv[2]; sA[kh][rq*4+3] = mv[3];
      }

    // ---- S^T = K Q^T : lane holds q=l31, k over regs ----
    __builtin_amdgcn_s_setprio(1);
    #pragma unroll
    for (int ds=0; ds<4; ++ds) {
      short8 kf0 = *(const short8*)(KsC + l31*128       + ((ds*32 + hi*16) ^ rsw));
      short8 kf1 = *(const short8*)(KsC + (l31+32)*128  + ((ds*32 + hi*16) ^ rsw));
      sA[0] = __builtin_amdgcn_mfma_f32_32x32x16_bf16(kf0, qf[ds], sA[0], 0,0,0);
      sA[1] = __builtin_amdgcn_mfma_f32_32x32x16_bf16(kf1, qf[ds], sA[1], 0,0,0);
    }
    __builtin_amdgcn_s_setprio(0);

    // ---- online softmax (in-register, log2 domain) ----
    float mx[8];
    #pragma unroll
    for (int r=0;r<8;++r)
      mx[r] = fmaxf(fmaxf(sA[0][r], sA[0][r+8]), fmaxf(sA[1][r], sA[1][r+8]));
    #pragma unroll
    for (int s=4; s>0; s>>=1)
      #pragma unroll
      for (int r=0;r<4;++r) if (r < s) mx[r] = fmaxf(mx[r], mx[r+s]);
    float tmx = mx[0];
    tmx = fmaxf(tmx, __shfl_xor(tmx, 32));

    // defer-max: only rescale when the running max grows materially (T13)
    if (!__all(tmx <= m_run + 8.0f)) {
      const float mnew = fmaxf(m_run, tmx);
      const float sc = exp2a(m_run - mnew);
      m_run = mnew;
      l_run *= sc;
      #pragma unroll
      for (int n=0;n<2;++n)
        #pragma unroll
        for (int r=0;r<16;++r) oA[n][r] *= sc;
    }

    f32x4 lp = {0.f,0.f,0.f,0.f};
    #pragma unroll
    for (int kh=0;kh<2;++kh)
      #pragma unroll
      for (int r=0;r<16;++r) {
        const float p = exp2a(sA[kh][r] - m_run);
        sA[kh][r] = p;
        lp[r&3] += p;
      }
    l_run += (lp[0]+lp[1]) + (lp[2]+lp[3]);

    // ---- P -> bf16 B-frags (shfl_xor half-exchange, known-good mapping) ----
    // target w[tt][w]: lane (q=l31,hi) holds keys (tt*16 + hi*8 + 2w, +1)
    unsigned w[4][4];
    const bool lo = (lane < 32);
    #pragma unroll
    for (int tt=0; tt<4; ++tt) {
      const int kh = tt>>1, ro = (tt&1)*8;
      unsigned c01 = cvtpk(sA[kh][ro+0], sA[kh][ro+1]);
      unsigned c23 = cvtpk(sA[kh][ro+2], sA[kh][ro+3]);
      unsigned c45 = cvtpk(sA[kh][ro+4], sA[kh][ro+5]);
      unsigned c67 = cvtpk(sA[kh][ro+6], sA[kh][ro+7]);
      unsigned s01 = __shfl_xor(c01, 32);
      unsigned s23 = __shfl_xor(c23, 32);
      unsigned s45 = __shfl_xor(c45, 32);
      unsigned s67 = __shfl_xor(c67, 32);
      w[tt][0] = lo ? c01 : s45;   // keys hi*8+0,1
      w[tt][1] = lo ? c23 : s67;   // keys hi*8+2,3
      w[tt][2] = lo ? s01 : c45;   // keys hi*8+4,5
      w[tt][3] = lo ? s23 : c67;   // keys hi*8+6,7
    }

    // ---- O^T += V^T P^T ----
    __builtin_amdgcn_s_setprio(1);
    #pragma unroll
    for (int n=0;n<2;++n) {
      #pragma unroll
      for (int tt=0;tt<4;++tt) {
        short8 vf = *(const short8*)(VsC + (n*32+l31)*128 + ((tt*32 + hi*16) ^ rsw));
        uint4v wp = {w[tt][0], w[tt][1], w[tt][2], w[tt][3]};
        oA[n] = __builtin_amdgcn_mfma_f32_32x32x16_bf16(vf, __builtin_bit_cast(short8, wp), oA[n], 0,0,0);
      }
    }
    __builtin_amdgcn_s_setprio(0);

    // ---- write next tile into the other buffer ----
    if (more) {
      #pragma unroll
      for (int c=0;c<2;++c){
        const int e = t + c*256; const int row = e>>3, sl = e&7;
        const int byte = row*128 + ((sl*16) ^ ((row&7)<<4));
        *(short8*)((char*)Ks[cur^1] + byte) = nk[c];
        *(short8*)((char*)Vs[cur^1] + byte) = nv[c];
      }
    }
    __syncthreads();
  }

  // ---- epilogue ----
  l_run += __shfl_xor(l_run, 32);
  const float inv = 1.0f / l_run;

  char* ot = (char*)Ks + wv*4096;   // 4KB per wave, reuse K LDS
  #pragma unroll
  for (int n=0;n<2;++n)
    #pragma unroll
    for (int rq=0;rq<4;++rq) {
      const unsigned w0 = cvtpk(oA[n][rq*4+0]*inv, oA[n][rq*4+1]*inv);
      const unsigned w1 = cvtpk(oA[n][rq*4+2]*inv, oA[n][rq*4+3]*inv);
      const int sl = n*4 + rq;
      const int byte = l31*128 + ((sl*16) ^ ((l31&7)<<4)) + hi*8;
      *(unsigned*)(ot + byte)     = w0;
      *(unsigned*)(ot + byte + 4) = w1;
    }
  asm volatile("s_waitcnt lgkmcnt(0)" ::: "memory");
  __builtin_amdgcn_sched_barrier(0);

  const int row = lane >> 1, half = lane & 1;
  const int orow = b*4096 + q0 + wv*32 + row;
  #pragma unroll
  for (int i=0;i<4;++i) {
    const int sl = half*4 + i;
    short8 vv = *(const short8*)(ot + row*128 + ((sl*16) ^ ((row&7)<<4)));
    *(short8*)(O + (size_t)orow*1024 + h*64 + half*32 + i*8) = vv;
  }
}

extern "C" void kernel_launch(void* const* d_in, const int* in_sizes, int n_in,
                              void* d_out, int out_size, void* d_ws, size_t ws_size,
                              hipStream_t stream)
{
  const float* q    = (const float*)d_in[0];
  const float* k    = (const float*)d_in[1];
  const float* v    = (const float*)d_in[2];
  const int*   mask = (const int*)d_in[3];
  const float* w_q  = (const float*)d_in[4];
  const float* b_q  = (const float*)d_in[5];
  const float* w_k  = (const float*)d_in[6];
  const float* b_k  = (const float*)d_in[7];
  const float* w_v  = (const float*)d_in[8];
  const float* b_v  = (const float*)d_in[9];
  const float* w_o  = (const float*)d_in[10];
  const float* b_o  = (const float*)d_in[11];
  float* out = (float*)d_out;

  char* ws = (char*)d_ws;
  const size_t SZ = (size_t)8192*1024*2;   // one bf16 [8192][1024] buffer
  short* QH = (short*)(ws);
  short* KH = (short*)(ws + SZ);
  short* OB = (short*)(ws + 2*SZ);         // V-proj output, then reused for attn out
  short* VT = (short*)(ws + 3*SZ);
  short* VH = OB;

  const float QSCALE = 0.125f * 1.44269504f;

  dim3 bG(256);
  dim3 gG(64, 8);
  hipLaunchKernelGGL((gemm_bt_kernel<float, short>), gG, bG, 0, stream, q, w_q, b_q, QH, 8192, 1024, 1024, QSCALE);
  hipLaunchKernelGGL((gemm_bt_kernel<float, short>), gG, bG, 0, stream, k, w_k, b_k, KH, 8192, 1024, 1024, 1.0f);
  hipLaunchKernelGGL((gemm_bt_kernel<float, short>), gG, bG, 0, stream, v, w_v, b_v, VH, 8192, 1024, 1024, 1.0f);
  hipLaunchKernelGGL(transpose_v_kernel, dim3(64, 32), bG, 0, stream, VH, VT);
  hipLaunchKernelGGL(flash_kernel, dim3(32, 32), bG, 0, stream, QH, KH, VT, mask, OB);
  hipLaunchKernelGGL((gemm_bt_kernel<short, float>), gG, bG, 0, stream, OB, w_o, b_o, out, 8192, 1024, 1024, 1.0f);
}

// Round 7
// 353.734 us; speedup vs baseline: 1.4542x; 1.0962x over previous
//
#include <hip/hip_runtime.h>
#include <hip/hip_bf16.h>
#include <stdint.h>
#include <type_traits>

typedef __attribute__((ext_vector_type(8))) short short8;
typedef __attribute__((ext_vector_type(4))) float f32x4;
typedef __attribute__((ext_vector_type(16))) float f32x16;
typedef __attribute__((ext_vector_type(4))) unsigned int uint4v;

#define DEV static __device__ __forceinline__

DEV short bf16b(float f) {
  return __builtin_bit_cast(short, __float2bfloat16(f));
}
DEV float exp2a(float x){ float r; asm("v_exp_f32 %0, %1" : "=v"(r) : "v"(x)); return r; }
DEV unsigned cvtpk(float lo, float hi){ unsigned r; asm("v_cvt_pk_bf16_f32 %0, %1, %2" : "=v"(r) : "v"(lo), "v"(hi)); return r; }
// NOTE: v_permlane32_swap_b32 via inline asm failed under BOTH operand orders
// (R3: documented vdst.hi<->vsrc.lo order; R5: reversed). Condemned — shfl_xor
// is the verified exchange path.

// ---------------- GEMM: C[m][n] = (sum_k A[m][k] * W[n][k] + bias[n]) * oscale ----
template<typename AT, typename OT>
__global__ __launch_bounds__(256)
void gemm_bt_kernel(const AT* __restrict__ A, const float* __restrict__ W,
                    const float* __restrict__ bias, OT* __restrict__ C,
                    int M, int N, int K, float oscale)
{
  __shared__ __align__(16) short As[128*32];
  __shared__ __align__(16) short Bs[128*32];
  const int t = threadIdx.x;
  const int lane = t & 63;
  const int wv = t >> 6;
  const int wr = wv >> 1, wc = wv & 1;
  const int l15 = lane & 15, lg = lane >> 4;
  const int m0 = blockIdx.x * 128;
  const int n0 = blockIdx.y * 128;

  f32x4 acc[4][4] = {};

  for (int k0 = 0; k0 < K; k0 += 32) {
    #pragma unroll
    for (int c = 0; c < 2; ++c) {
      const int e = t + c*256;
      const int row = e >> 2;
      const int col = (e & 3) * 8;
      const int byte = row*64 + ((col*2) ^ ((row&6)<<3));
      short8 va;
      if constexpr (std::is_same<AT,float>::value) {
        const float* src = A + (size_t)(m0+row)*K + k0 + col;
        f32x4 f0 = *(const f32x4*)src;
        f32x4 f1 = *(const f32x4*)(src+4);
        #pragma unroll
        for (int j=0;j<4;++j){ va[j]=bf16b(f0[j]); va[4+j]=bf16b(f1[j]); }
      } else {
        va = *(const short8*)(A + (size_t)(m0+row)*K + k0 + col);
      }
      *(short8*)((char*)As + byte) = va;
      const float* srcB = W + (size_t)(n0+row)*K + k0 + col;
      f32x4 g0 = *(const f32x4*)srcB;
      f32x4 g1 = *(const f32x4*)(srcB+4);
      short8 vb;
      #pragma unroll
      for (int j=0;j<4;++j){ vb[j]=bf16b(g0[j]); vb[4+j]=bf16b(g1[j]); }
      *(short8*)((char*)Bs + byte) = vb;
    }
    __syncthreads();
    short8 af[4], bfr[4];
    #pragma unroll
    for (int m=0;m<4;++m) {
      const int row = wr*64 + m*16 + l15;
      af[m] = *(const short8*)((const char*)As + row*64 + ((lg*16) ^ ((row&6)<<3)));
    }
    #pragma unroll
    for (int n=0;n<4;++n) {
      const int row = wc*64 + n*16 + l15;
      bfr[n] = *(const short8*)((const char*)Bs + row*64 + ((lg*16) ^ ((row&6)<<3)));
    }
    #pragma unroll
    for (int m=0;m<4;++m)
      #pragma unroll
      for (int n=0;n<4;++n)
        acc[m][n] = __builtin_amdgcn_mfma_f32_16x16x32_bf16(af[m], bfr[n], acc[m][n], 0, 0, 0);
    __syncthreads();
  }

  #pragma unroll
  for (int n=0;n<4;++n) {
    const int col = n0 + wc*64 + n*16 + l15;
    const float bv = bias[col];
    #pragma unroll
    for (int m=0;m<4;++m) {
      #pragma unroll
      for (int i=0;i<4;++i) {
        const int row = m0 + wr*64 + m*16 + lg*4 + i;
        const float val = (acc[m][n][i] + bv) * oscale;
        if constexpr (std::is_same<OT,float>::value) C[(size_t)row*N + col] = val;
        else                                         C[(size_t)row*N + col] = bf16b(val);
      }
    }
  }
}

// ---------------- V transpose: Vh[b*4096+s][h*64+dk] -> Vt[(b*16+h)*64+dk][s] ----
__global__ __launch_bounds__(256)
void transpose_v_kernel(const short* __restrict__ Vh, short* __restrict__ Vt)
{
  __shared__ short tile[64][65];
  const int t = threadIdx.x;
  const int bh = blockIdx.y, b = bh >> 4, h = bh & 15;
  const int s0 = blockIdx.x * 64;
  const int r = t >> 2;
  const int c = (t & 3) * 16;
  const short* src = Vh + (size_t)(b*4096 + s0 + r)*1024 + h*64 + c;
  short8 v0 = *(const short8*)src;
  short8 v1 = *(const short8*)(src + 8);
  #pragma unroll
  for (int j=0;j<8;++j){ tile[r][c+j]=v0[j]; tile[r][c+8+j]=v1[j]; }
  __syncthreads();
  short8 o0, o1;
  #pragma unroll
  for (int j=0;j<8;++j){ o0[j]=tile[c+j][r]; o1[j]=tile[c+8+j][r]; }
  short* dst = Vt + (size_t)(bh*64 + r)*4096 + s0 + c;
  *(short8*)dst = o0;
  *(short8*)(dst+8) = o1;
}

// ---------------- Flash attention, swapped-QK 32x32 structure ----------------
// Grid (16 q-blocks, 32 bh). 512 thr = 8 waves; wave owns 32 q-rows (QBLK=256).
// 2 blocks/CU co-resident (48KB LDS), 16 waves/CU.
// Per lane: q = lane&31 for scores, l, m, AND O^T accumulator.
__global__ __launch_bounds__(512)
void flash_kernel(const short* __restrict__ Qh, const short* __restrict__ Kh,
                  const short* __restrict__ Vt, const int* __restrict__ mask,
                  short* __restrict__ O)
{
  __shared__ __align__(16) char smem[49152];
  short* KsBuf = (short*)smem;               // [2][64*64] = 16KB
  short* VsBuf = (short*)(smem + 16384);     // [2][64*64] = 16KB
  float* MaskF = (float*)(smem + 32768);     // [4096]     = 16KB

  const int t = threadIdx.x;
  const int lane = t & 63, wv = t >> 6;
  const int l31 = lane & 31, hi = lane >> 5;
  const int rsw = (l31 & 7) << 4;
  const int bh = blockIdx.y, b = bh >> 4, h = bh & 15;
  const int q0 = blockIdx.x * 256;

  // mask -> additive float (log2 domain), once per block
  for (int i = t; i < 4096; i += 512)
    MaskF[i] = (mask[b*4096 + i] == 0) ? -1.0e9f : 0.0f;

  // Q B-frags (already scaled by 0.125*log2e in the Q projection)
  short8 qf[4];
  {
    const short* qrow = Qh + (size_t)(b*4096 + q0 + wv*32 + l31)*1024 + h*64;
    #pragma unroll
    for (int ds=0; ds<4; ++ds)
      qf[ds] = *(const short8*)(qrow + ds*16 + hi*8);
  }

  float m_run = -3.0e38f;
  float l_run = 0.0f;
  f32x16 oA[2] = {};

  // prologue: stage tile 0 (512 threads: 1 K + 1 V short8 each)
  {
    const int row = t >> 3, sl = t & 7;
    const int byte = row*128 + ((sl*16) ^ ((row&7)<<4));
    *(short8*)((char*)KsBuf + byte) =
      *(const short8*)(Kh + (size_t)(b*4096 + row)*1024 + h*64 + sl*8);
    *(short8*)((char*)VsBuf + byte) =
      *(const short8*)(Vt + (size_t)(bh*64 + row)*4096 + sl*8);
  }
  __syncthreads();

  for (int kt = 0; kt < 64; ++kt) {
    const int cur = kt & 1;
    const char* KsC = (const char*)KsBuf + cur*8192;
    const char* VsC = (const char*)VsBuf + cur*8192;
    const bool more = (kt + 1 < 64);

    // issue next-tile global loads early (latency hides under QK+softmax+PV)
    short8 nk, nv;
    const int srow = t >> 3, ssl = t & 7;
    if (more) {
      nk = *(const short8*)(Kh + (size_t)(b*4096 + (kt+1)*64 + srow)*1024 + h*64 + ssl*8);
      nv = *(const short8*)(Vt + (size_t)(bh*64 + srow)*4096 + (kt+1)*64 + ssl*8);
    }

    // ---- S accumulator init = additive mask (keys per C-layout: (r&3)+8*(r>>2)+4*hi) ----
    f32x16 sA[2];
    #pragma unroll
    for (int kh=0;kh<2;++kh)
      #pragma unroll
      for (int rq=0;rq<4;++rq) {
        f32x4 mv = *(const f32x4*)(&MaskF[kt*64 + kh*32 + rq*8 + hi*4]);
        sA[kh][rq*4+0] = mv[0]; sA[kh][rq*4+1] = mv[1];
        sA[kh][rq*4+2] = mv[2]; sA[kh][rq*4+3] = mv[3];
      }

    // ---- S^T = K Q^T : lane holds q=l31, k over regs ----
    __builtin_amdgcn_s_setprio(1);
    #pragma unroll
    for (int ds=0; ds<4; ++ds) {
      short8 kf0 = *(const short8*)(KsC + l31*128       + ((ds*32 + hi*16) ^ rsw));
      short8 kf1 = *(const short8*)(KsC + (l31+32)*128  + ((ds*32 + hi*16) ^ rsw));
      sA[0] = __builtin_amdgcn_mfma_f32_32x32x16_bf16(kf0, qf[ds], sA[0], 0,0,0);
      sA[1] = __builtin_amdgcn_mfma_f32_32x32x16_bf16(kf1, qf[ds], sA[1], 0,0,0);
    }
    __builtin_amdgcn_s_setprio(0);

    // ---- online softmax (in-register, log2 domain) ----
    float mx[8];
    #pragma unroll
    for (int r=0;r<8;++r)
      mx[r] = fmaxf(fmaxf(sA[0][r], sA[0][r+8]), fmaxf(sA[1][r], sA[1][r+8]));
    #pragma unroll
    for (int s=4; s>0; s>>=1)
      #pragma unroll
      for (int r=0;r<4;++r) if (r < s) mx[r] = fmaxf(mx[r], mx[r+s]);
    float tmx = mx[0];
    tmx = fmaxf(tmx, __shfl_xor(tmx, 32));

    // defer-max: only rescale when the running max grows materially (T13)
    if (!__all(tmx <= m_run + 8.0f)) {
      const float mnew = fmaxf(m_run, tmx);
      const float sc = exp2a(m_run - mnew);
      m_run = mnew;
      l_run *= sc;
      #pragma unroll
      for (int n=0;n<2;++n)
        #pragma unroll
        for (int r=0;r<16;++r) oA[n][r] *= sc;
    }

    f32x4 lp = {0.f,0.f,0.f,0.f};
    #pragma unroll
    for (int kh=0;kh<2;++kh)
      #pragma unroll
      for (int r=0;r<16;++r) {
        const float p = exp2a(sA[kh][r] - m_run);
        sA[kh][r] = p;
        lp[r&3] += p;
      }
    l_run += (lp[0]+lp[1]) + (lp[2]+lp[3]);

    // ---- P -> bf16 B-frags (shfl_xor half-exchange, known-good mapping) ----
    // target w[tt][w]: lane (q=l31,hi) holds keys (tt*16 + hi*8 + 2w, +1)
    unsigned w[4][4];
    const bool lo = (lane < 32);
    #pragma unroll
    for (int tt=0; tt<4; ++tt) {
      const int kh = tt>>1, ro = (tt&1)*8;
      unsigned c01 = cvtpk(sA[kh][ro+0], sA[kh][ro+1]);
      unsigned c23 = cvtpk(sA[kh][ro+2], sA[kh][ro+3]);
      unsigned c45 = cvtpk(sA[kh][ro+4], sA[kh][ro+5]);
      unsigned c67 = cvtpk(sA[kh][ro+6], sA[kh][ro+7]);
      unsigned s01 = __shfl_xor(c01, 32);
      unsigned s23 = __shfl_xor(c23, 32);
      unsigned s45 = __shfl_xor(c45, 32);
      unsigned s67 = __shfl_xor(c67, 32);
      w[tt][0] = lo ? c01 : s45;   // keys hi*8+0,1
      w[tt][1] = lo ? c23 : s67;   // keys hi*8+2,3
      w[tt][2] = lo ? s01 : c45;   // keys hi*8+4,5
      w[tt][3] = lo ? s23 : c67;   // keys hi*8+6,7
    }

    // ---- O^T += V^T P^T ----
    __builtin_amdgcn_s_setprio(1);
    #pragma unroll
    for (int n=0;n<2;++n) {
      #pragma unroll
      for (int tt=0;tt<4;++tt) {
        short8 vf = *(const short8*)(VsC + (n*32+l31)*128 + ((tt*32 + hi*16) ^ rsw));
        uint4v wp = {w[tt][0], w[tt][1], w[tt][2], w[tt][3]};
        oA[n] = __builtin_amdgcn_mfma_f32_32x32x16_bf16(vf, __builtin_bit_cast(short8, wp), oA[n], 0,0,0);
      }
    }
    __builtin_amdgcn_s_setprio(0);

    // ---- write next tile into the other buffer ----
    if (more) {
      const int byte = srow*128 + ((ssl*16) ^ ((srow&7)<<4));
      *(short8*)((char*)KsBuf + (cur^1)*8192 + byte) = nk;
      *(short8*)((char*)VsBuf + (cur^1)*8192 + byte) = nv;
    }
    __syncthreads();
  }

  // ---- epilogue ----
  l_run += __shfl_xor(l_run, 32);
  const float inv = 1.0f / l_run;

  char* ot = smem + wv*4096;   // 4KB per wave (8 waves = 32KB, within Ks+Vs)
  #pragma unroll
  for (int n=0;n<2;++n)
    #pragma unroll
    for (int rq=0;rq<4;++rq) {
      const unsigned w0 = cvtpk(oA[n][rq*4+0]*inv, oA[n][rq*4+1]*inv);
      const unsigned w1 = cvtpk(oA[n][rq*4+2]*inv, oA[n][rq*4+3]*inv);
      const int sl = n*4 + rq;
      const int byte = l31*128 + ((sl*16) ^ ((l31&7)<<4)) + hi*8;
      *(unsigned*)(ot + byte)     = w0;
      *(unsigned*)(ot + byte + 4) = w1;
    }
  asm volatile("s_waitcnt lgkmcnt(0)" ::: "memory");
  __builtin_amdgcn_sched_barrier(0);

  const int row = lane >> 1, half = lane & 1;
  const int orow = b*4096 + q0 + wv*32 + row;
  #pragma unroll
  for (int i=0;i<4;++i) {
    const int sl = half*4 + i;
    short8 vv = *(const short8*)(ot + row*128 + ((sl*16) ^ ((row&7)<<4)));
    *(short8*)(O + (size_t)orow*1024 + h*64 + half*32 + i*8) = vv;
  }
}

extern "C" void kernel_launch(void* const* d_in, const int* in_sizes, int n_in,
                              void* d_out, int out_size, void* d_ws, size_t ws_size,
                              hipStream_t stream)
{
  const float* q    = (const float*)d_in[0];
  const float* k    = (const float*)d_in[1];
  const float* v    = (const float*)d_in[2];
  const int*   mask = (const int*)d_in[3];
  const float* w_q  = (const float*)d_in[4];
  const float* b_q  = (const float*)d_in[5];
  const float* w_k  = (const float*)d_in[6];
  const float* b_k  = (const float*)d_in[7];
  const float* w_v  = (const float*)d_in[8];
  const float* b_v  = (const float*)d_in[9];
  const float* w_o  = (const float*)d_in[10];
  const float* b_o  = (const float*)d_in[11];
  float* out = (float*)d_out;

  char* ws = (char*)d_ws;
  const size_t SZ = (size_t)8192*1024*2;   // one bf16 [8192][1024] buffer
  short* QH = (short*)(ws);
  short* KH = (short*)(ws + SZ);
  short* OB = (short*)(ws + 2*SZ);         // V-proj output, then reused for attn out
  short* VT = (short*)(ws + 3*SZ);
  short* VH = OB;

  const float QSCALE = 0.125f * 1.44269504f;

  dim3 bG(256);
  dim3 gG(64, 8);
  hipLaunchKernelGGL((gemm_bt_kernel<float, short>), gG, bG, 0, stream, q, w_q, b_q, QH, 8192, 1024, 1024, QSCALE);
  hipLaunchKernelGGL((gemm_bt_kernel<float, short>), gG, bG, 0, stream, k, w_k, b_k, KH, 8192, 1024, 1024, 1.0f);
  hipLaunchKernelGGL((gemm_bt_kernel<float, short>), gG, bG, 0, stream, v, w_v, b_v, VH, 8192, 1024, 1024, 1.0f);
  hipLaunchKernelGGL(transpose_v_kernel, dim3(64, 32), bG, 0, stream, VH, VT);
  hipLaunchKernelGGL(flash_kernel, dim3(16, 32), dim3(512), 0, stream, QH, KH, VT, mask, OB);
  hipLaunchKernelGGL((gemm_bt_kernel<short, float>), gG, bG, 0, stream, OB, w_o, b_o, out, 8192, 1024, 1024, 1.0f);
}

// Round 8
// 350.271 us; speedup vs baseline: 1.4686x; 1.0099x over previous
//
#include <hip/hip_runtime.h>
#include <hip/hip_bf16.h>
#include <stdint.h>
#include <type_traits>

typedef __attribute__((ext_vector_type(8))) short short8;
typedef __attribute__((ext_vector_type(4))) float f32x4;
typedef __attribute__((ext_vector_type(16))) float f32x16;
typedef __attribute__((ext_vector_type(4))) unsigned int uint4v;

#define DEV static __device__ __forceinline__

DEV short bf16b(float f) {
  return __builtin_bit_cast(short, __float2bfloat16(f));
}
DEV float exp2a(float x){ float r; asm("v_exp_f32 %0, %1" : "=v"(r) : "v"(x)); return r; }
DEV unsigned cvtpk(float lo, float hi){ unsigned r; asm("v_cvt_pk_bf16_f32 %0, %1, %2" : "=v"(r) : "v"(lo), "v"(hi)); return r; }
// NOTE: v_permlane32_swap_b32 via inline asm failed under BOTH operand orders
// (R3/R5). Condemned — shfl_xor is the verified exchange path.

// ---------------- GEMM: C[m][n] = (sum_k A[m][k] * W[n][k] + bias[n]) * oscale ----
template<typename AT, typename OT>
__global__ __launch_bounds__(256)
void gemm_bt_kernel(const AT* __restrict__ A, const float* __restrict__ W,
                    const float* __restrict__ bias, OT* __restrict__ C,
                    int M, int N, int K, float oscale)
{
  __shared__ __align__(16) short As[128*32];
  __shared__ __align__(16) short Bs[128*32];
  const int t = threadIdx.x;
  const int lane = t & 63;
  const int wv = t >> 6;
  const int wr = wv >> 1, wc = wv & 1;
  const int l15 = lane & 15, lg = lane >> 4;
  const int m0 = blockIdx.x * 128;
  const int n0 = blockIdx.y * 128;

  f32x4 acc[4][4] = {};

  for (int k0 = 0; k0 < K; k0 += 32) {
    #pragma unroll
    for (int c = 0; c < 2; ++c) {
      const int e = t + c*256;
      const int row = e >> 2;
      const int col = (e & 3) * 8;
      const int byte = row*64 + ((col*2) ^ ((row&6)<<3));
      short8 va;
      if constexpr (std::is_same<AT,float>::value) {
        const float* src = A + (size_t)(m0+row)*K + k0 + col;
        f32x4 f0 = *(const f32x4*)src;
        f32x4 f1 = *(const f32x4*)(src+4);
        #pragma unroll
        for (int j=0;j<4;++j){ va[j]=bf16b(f0[j]); va[4+j]=bf16b(f1[j]); }
      } else {
        va = *(const short8*)(A + (size_t)(m0+row)*K + k0 + col);
      }
      *(short8*)((char*)As + byte) = va;
      const float* srcB = W + (size_t)(n0+row)*K + k0 + col;
      f32x4 g0 = *(const f32x4*)srcB;
      f32x4 g1 = *(const f32x4*)(srcB+4);
      short8 vb;
      #pragma unroll
      for (int j=0;j<4;++j){ vb[j]=bf16b(g0[j]); vb[4+j]=bf16b(g1[j]); }
      *(short8*)((char*)Bs + byte) = vb;
    }
    __syncthreads();
    short8 af[4], bfr[4];
    #pragma unroll
    for (int m=0;m<4;++m) {
      const int row = wr*64 + m*16 + l15;
      af[m] = *(const short8*)((const char*)As + row*64 + ((lg*16) ^ ((row&6)<<3)));
    }
    #pragma unroll
    for (int n=0;n<4;++n) {
      const int row = wc*64 + n*16 + l15;
      bfr[n] = *(const short8*)((const char*)Bs + row*64 + ((lg*16) ^ ((row&6)<<3)));
    }
    #pragma unroll
    for (int m=0;m<4;++m)
      #pragma unroll
      for (int n=0;n<4;++n)
        acc[m][n] = __builtin_amdgcn_mfma_f32_16x16x32_bf16(af[m], bfr[n], acc[m][n], 0, 0, 0);
    __syncthreads();
  }

  #pragma unroll
  for (int n=0;n<4;++n) {
    const int col = n0 + wc*64 + n*16 + l15;
    const float bv = bias[col];
    #pragma unroll
    for (int m=0;m<4;++m) {
      #pragma unroll
      for (int i=0;i<4;++i) {
        const int row = m0 + wr*64 + m*16 + lg*4 + i;
        const float val = (acc[m][n][i] + bv) * oscale;
        if constexpr (std::is_same<OT,float>::value) C[(size_t)row*N + col] = val;
        else                                         C[(size_t)row*N + col] = bf16b(val);
      }
    }
  }
}

// ---------------- V transpose: Vh[b*4096+s][h*64+dk] -> Vt[(b*16+h)*64+dk][s] ----
__global__ __launch_bounds__(256)
void transpose_v_kernel(const short* __restrict__ Vh, short* __restrict__ Vt)
{
  __shared__ short tile[64][65];
  const int t = threadIdx.x;
  const int bh = blockIdx.y, b = bh >> 4, h = bh & 15;
  const int s0 = blockIdx.x * 64;
  const int r = t >> 2;
  const int c = (t & 3) * 16;
  const short* src = Vh + (size_t)(b*4096 + s0 + r)*1024 + h*64 + c;
  short8 v0 = *(const short8*)src;
  short8 v1 = *(const short8*)(src + 8);
  #pragma unroll
  for (int j=0;j<8;++j){ tile[r][c+j]=v0[j]; tile[r][c+8+j]=v1[j]; }
  __syncthreads();
  short8 o0, o1;
  #pragma unroll
  for (int j=0;j<8;++j){ o0[j]=tile[c+j][r]; o1[j]=tile[c+8+j][r]; }
  short* dst = Vt + (size_t)(bh*64 + r)*4096 + s0 + c;
  *(short8*)dst = o0;
  *(short8*)(dst+8) = o1;
}

// ---------------- Flash attention, swapped-QK 32x32 structure ----------------
// Grid (32 q-blocks, 32 bh). 256 thr = 4 waves; wave owns 32 q-rows (QBLK=128).
// __launch_bounds__(256,3): 3 blocks/CU co-resident (48KB LDS x3 = 144KB,
// regs <= 170/wave), 12 waves/CU.
// Per lane: q = lane&31 for scores, l, m, AND O^T accumulator.
__global__ __launch_bounds__(256, 3)
void flash_kernel(const short* __restrict__ Qh, const short* __restrict__ Kh,
                  const short* __restrict__ Vt, const int* __restrict__ mask,
                  short* __restrict__ O)
{
  __shared__ __align__(16) char smem[49152];
  short* KsBuf = (short*)smem;               // [2][64*64] = 16KB
  short* VsBuf = (short*)(smem + 16384);     // [2][64*64] = 16KB
  float* MaskF = (float*)(smem + 32768);     // [4096]     = 16KB

  const int t = threadIdx.x;
  const int lane = t & 63, wv = t >> 6;
  const int l31 = lane & 31, hi = lane >> 5;
  const int rsw = (l31 & 7) << 4;
  const int bh = blockIdx.y, b = bh >> 4, h = bh & 15;
  const int q0 = blockIdx.x * 128;

  // mask -> additive float (log2 domain), once per block
  for (int i = t; i < 4096; i += 256)
    MaskF[i] = (mask[b*4096 + i] == 0) ? -1.0e9f : 0.0f;

  // Q B-frags (already scaled by 0.125*log2e in the Q projection)
  short8 qf[4];
  {
    const short* qrow = Qh + (size_t)(b*4096 + q0 + wv*32 + l31)*1024 + h*64;
    #pragma unroll
    for (int ds=0; ds<4; ++ds)
      qf[ds] = *(const short8*)(qrow + ds*16 + hi*8);
  }

  float m_run = -3.0e38f;
  float l_run = 0.0f;
  f32x16 oA[2] = {};

  // prologue: stage tile 0 (256 threads: 2 K + 2 V short8 each)
  #pragma unroll
  for (int c = 0; c < 2; ++c) {
    const int e = t + c*256;
    const int row = e >> 3, sl = e & 7;
    const int byte = row*128 + ((sl*16) ^ ((row&7)<<4));
    *(short8*)((char*)KsBuf + byte) =
      *(const short8*)(Kh + (size_t)(b*4096 + row)*1024 + h*64 + sl*8);
    *(short8*)((char*)VsBuf + byte) =
      *(const short8*)(Vt + (size_t)(bh*64 + row)*4096 + sl*8);
  }
  __syncthreads();

  for (int kt = 0; kt < 64; ++kt) {
    const int cur = kt & 1;
    const char* KsC = (const char*)KsBuf + cur*8192;
    const char* VsC = (const char*)VsBuf + cur*8192;
    const bool more = (kt + 1 < 64);

    // issue next-tile global loads early (latency hides under QK+softmax+PV)
    short8 nk[2], nv[2];
    if (more) {
      #pragma unroll
      for (int c=0;c<2;++c){
        const int e = t + c*256; const int row = e>>3, sl = e&7;
        nk[c] = *(const short8*)(Kh + (size_t)(b*4096 + (kt+1)*64 + row)*1024 + h*64 + sl*8);
        nv[c] = *(const short8*)(Vt + (size_t)(bh*64 + row)*4096 + (kt+1)*64 + sl*8);
      }
    }

    // ---- S accumulator init = additive mask (keys per C-layout: (r&3)+8*(r>>2)+4*hi) ----
    f32x16 sA[2];
    #pragma unroll
    for (int kh=0;kh<2;++kh)
      #pragma unroll
      for (int rq=0;rq<4;++rq) {
        f32x4 mv = *(const f32x4*)(&MaskF[kt*64 + kh*32 + rq*8 + hi*4]);
        sA[kh][rq*4+0] = mv[0]; sA[kh][rq*4+1] = mv[1];
        sA[kh][rq*4+2] = mv[2]; sA[kh][rq*4+3] = mv[3];
      }

    // ---- S^T = K Q^T : lane holds q=l31, k over regs ----
    __builtin_amdgcn_s_setprio(1);
    #pragma unroll
    for (int ds=0; ds<4; ++ds) {
      short8 kf0 = *(const short8*)(KsC + l31*128       + ((ds*32 + hi*16) ^ rsw));
      short8 kf1 = *(const short8*)(KsC + (l31+32)*128  + ((ds*32 + hi*16) ^ rsw));
      sA[0] = __builtin_amdgcn_mfma_f32_32x32x16_bf16(kf0, qf[ds], sA[0], 0,0,0);
      sA[1] = __builtin_amdgcn_mfma_f32_32x32x16_bf16(kf1, qf[ds], sA[1], 0,0,0);
    }
    __builtin_amdgcn_s_setprio(0);

    // ---- online softmax (in-register, log2 domain) ----
    float mx[8];
    #pragma unroll
    for (int r=0;r<8;++r)
      mx[r] = fmaxf(fmaxf(sA[0][r], sA[0][r+8]), fmaxf(sA[1][r], sA[1][r+8]));
    #pragma unroll
    for (int s=4; s>0; s>>=1)
      #pragma unroll
      for (int r=0;r<4;++r) if (r < s) mx[r] = fmaxf(mx[r], mx[r+s]);
    float tmx = mx[0];
    tmx = fmaxf(tmx, __shfl_xor(tmx, 32));

    // defer-max: only rescale when the running max grows materially (T13)
    if (!__all(tmx <= m_run + 8.0f)) {
      const float mnew = fmaxf(m_run, tmx);
      const float sc = exp2a(m_run - mnew);
      m_run = mnew;
      l_run *= sc;
      #pragma unroll
      for (int n=0;n<2;++n)
        #pragma unroll
        for (int r=0;r<16;++r) oA[n][r] *= sc;
    }

    f32x4 lp = {0.f,0.f,0.f,0.f};
    #pragma unroll
    for (int kh=0;kh<2;++kh)
      #pragma unroll
      for (int r=0;r<16;++r) {
        const float p = exp2a(sA[kh][r] - m_run);
        sA[kh][r] = p;
        lp[r&3] += p;
      }
    l_run += (lp[0]+lp[1]) + (lp[2]+lp[3]);

    // ---- P -> bf16 B-frags (shfl_xor half-exchange, known-good mapping) ----
    // target w[tt][w]: lane (q=l31,hi) holds keys (tt*16 + hi*8 + 2w, +1)
    unsigned w[4][4];
    const bool lo = (lane < 32);
    #pragma unroll
    for (int tt=0; tt<4; ++tt) {
      const int kh = tt>>1, ro = (tt&1)*8;
      unsigned c01 = cvtpk(sA[kh][ro+0], sA[kh][ro+1]);
      unsigned c23 = cvtpk(sA[kh][ro+2], sA[kh][ro+3]);
      unsigned c45 = cvtpk(sA[kh][ro+4], sA[kh][ro+5]);
      unsigned c67 = cvtpk(sA[kh][ro+6], sA[kh][ro+7]);
      unsigned s01 = __shfl_xor(c01, 32);
      unsigned s23 = __shfl_xor(c23, 32);
      unsigned s45 = __shfl_xor(c45, 32);
      unsigned s67 = __shfl_xor(c67, 32);
      w[tt][0] = lo ? c01 : s45;   // keys hi*8+0,1
      w[tt][1] = lo ? c23 : s67;   // keys hi*8+2,3
      w[tt][2] = lo ? s01 : c45;   // keys hi*8+4,5
      w[tt][3] = lo ? s23 : c67;   // keys hi*8+6,7
    }

    // ---- O^T += V^T P^T ----
    __builtin_amdgcn_s_setprio(1);
    #pragma unroll
    for (int n=0;n<2;++n) {
      #pragma unroll
      for (int tt=0;tt<4;++tt) {
        short8 vf = *(const short8*)(VsC + (n*32+l31)*128 + ((tt*32 + hi*16) ^ rsw));
        uint4v wp = {w[tt][0], w[tt][1], w[tt][2], w[tt][3]};
        oA[n] = __builtin_amdgcn_mfma_f32_32x32x16_bf16(vf, __builtin_bit_cast(short8, wp), oA[n], 0,0,0);
      }
    }
    __builtin_amdgcn_s_setprio(0);

    // ---- write next tile into the other buffer ----
    if (more) {
      #pragma unroll
      for (int c=0;c<2;++c){
        const int e = t + c*256; const int row = e>>3, sl = e&7;
        const int byte = row*128 + ((sl*16) ^ ((row&7)<<4));
        *(short8*)((char*)KsBuf + (cur^1)*8192 + byte) = nk[c];
        *(short8*)((char*)VsBuf + (cur^1)*8192 + byte) = nv[c];
      }
    }
    __syncthreads();
  }

  // ---- epilogue ----
  l_run += __shfl_xor(l_run, 32);
  const float inv = 1.0f / l_run;

  char* ot = smem + wv*4096;   // 4KB per wave (4 waves = 16KB)
  #pragma unroll
  for (int n=0;n<2;++n)
    #pragma unroll
    for (int rq=0;rq<4;++rq) {
      const unsigned w0 = cvtpk(oA[n][rq*4+0]*inv, oA[n][rq*4+1]*inv);
      const unsigned w1 = cvtpk(oA[n][rq*4+2]*inv, oA[n][rq*4+3]*inv);
      const int sl = n*4 + rq;
      const int byte = l31*128 + ((sl*16) ^ ((l31&7)<<4)) + hi*8;
      *(unsigned*)(ot + byte)     = w0;
      *(unsigned*)(ot + byte + 4) = w1;
    }
  asm volatile("s_waitcnt lgkmcnt(0)" ::: "memory");
  __builtin_amdgcn_sched_barrier(0);

  const int row = lane >> 1, half = lane & 1;
  const int orow = b*4096 + q0 + wv*32 + row;
  #pragma unroll
  for (int i=0;i<4;++i) {
    const int sl = half*4 + i;
    short8 vv = *(const short8*)(ot + row*128 + ((sl*16) ^ ((row&7)<<4)));
    *(short8*)(O + (size_t)orow*1024 + h*64 + half*32 + i*8) = vv;
  }
}

extern "C" void kernel_launch(void* const* d_in, const int* in_sizes, int n_in,
                              void* d_out, int out_size, void* d_ws, size_t ws_size,
                              hipStream_t stream)
{
  const float* q    = (const float*)d_in[0];
  const float* k    = (const float*)d_in[1];
  const float* v    = (const float*)d_in[2];
  const int*   mask = (const int*)d_in[3];
  const float* w_q  = (const float*)d_in[4];
  const float* b_q  = (const float*)d_in[5];
  const float* w_k  = (const float*)d_in[6];
  const float* b_k  = (const float*)d_in[7];
  const float* w_v  = (const float*)d_in[8];
  const float* b_v  = (const float*)d_in[9];
  const float* w_o  = (const float*)d_in[10];
  const float* b_o  = (const float*)d_in[11];
  float* out = (float*)d_out;

  char* ws = (char*)d_ws;
  const size_t SZ = (size_t)8192*1024*2;   // one bf16 [8192][1024] buffer
  short* QH = (short*)(ws);
  short* KH = (short*)(ws + SZ);
  short* OB = (short*)(ws + 2*SZ);         // V-proj output, then reused for attn out
  short* VT = (short*)(ws + 3*SZ);
  short* VH = OB;

  const float QSCALE = 0.125f * 1.44269504f;

  dim3 bG(256);
  dim3 gG(64, 8);
  hipLaunchKernelGGL((gemm_bt_kernel<float, short>), gG, bG, 0, stream, q, w_q, b_q, QH, 8192, 1024, 1024, QSCALE);
  hipLaunchKernelGGL((gemm_bt_kernel<float, short>), gG, bG, 0, stream, k, w_k, b_k, KH, 8192, 1024, 1024, 1.0f);
  hipLaunchKernelGGL((gemm_bt_kernel<float, short>), gG, bG, 0, stream, v, w_v, b_v, VH, 8192, 1024, 1024, 1.0f);
  hipLaunchKernelGGL(transpose_v_kernel, dim3(64, 32), bG, 0, stream, VH, VT);
  hipLaunchKernelGGL(flash_kernel, dim3(32, 32), dim3(256), 0, stream, QH, KH, VT, mask, OB);
  hipLaunchKernelGGL((gemm_bt_kernel<short, float>), gG, bG, 0, stream, OB, w_o, b_o, out, 8192, 1024, 1024, 1.0f);
}

// Round 9
// 327.714 us; speedup vs baseline: 1.5696x; 1.0688x over previous
//
#include <hip/hip_runtime.h>
#include <hip/hip_bf16.h>
#include <stdint.h>
#include <type_traits>

typedef __attribute__((ext_vector_type(8))) short short8;
typedef __attribute__((ext_vector_type(4))) float f32x4;
typedef __attribute__((ext_vector_type(16))) float f32x16;
typedef __attribute__((ext_vector_type(4))) unsigned int uint4v;
typedef __attribute__((ext_vector_type(2))) unsigned int uint2v;

#define DEV static __device__ __forceinline__

DEV short bf16b(float f) {
  return __builtin_bit_cast(short, __float2bfloat16(f));
}
DEV float exp2a(float x){ float r; asm("v_exp_f32 %0, %1" : "=v"(r) : "v"(x)); return r; }
DEV unsigned cvtpk(float lo, float hi){ unsigned r; asm("v_cvt_pk_bf16_f32 %0, %1, %2" : "=v"(r) : "v"(lo), "v"(hi)); return r; }
// v_permlane32_swap via the BUILTIN (proper IR modeling; returns both halves).
// Semantics: vdst.hi <-> vsrc.lo, i.e. swap(a,b) -> { [a.lo|b.lo], [a.hi|b.hi] }.
// (Inline-asm "+v","+v" form was condemned in R3/R5 — failed under both operand
// orders; the two tied read-write asm operands are mis-modeled.)
DEV uint2v plswap(unsigned a, unsigned b){
  return __builtin_amdgcn_permlane32_swap(a, b, false, false);
}

// ---------------- GEMM: C[m][n] = (sum_k A[m][k] * W[n][k] + bias[n]) * oscale ----
template<typename AT, typename OT>
__global__ __launch_bounds__(256)
void gemm_bt_kernel(const AT* __restrict__ A, const float* __restrict__ W,
                    const float* __restrict__ bias, OT* __restrict__ C,
                    int M, int N, int K, float oscale)
{
  __shared__ __align__(16) short As[128*32];
  __shared__ __align__(16) short Bs[128*32];
  const int t = threadIdx.x;
  const int lane = t & 63;
  const int wv = t >> 6;
  const int wr = wv >> 1, wc = wv & 1;
  const int l15 = lane & 15, lg = lane >> 4;
  const int m0 = blockIdx.x * 128;
  const int n0 = blockIdx.y * 128;

  f32x4 acc[4][4] = {};

  for (int k0 = 0; k0 < K; k0 += 32) {
    #pragma unroll
    for (int c = 0; c < 2; ++c) {
      const int e = t + c*256;
      const int row = e >> 2;
      const int col = (e & 3) * 8;
      const int byte = row*64 + ((col*2) ^ ((row&6)<<3));
      short8 va;
      if constexpr (std::is_same<AT,float>::value) {
        const float* src = A + (size_t)(m0+row)*K + k0 + col;
        f32x4 f0 = *(const f32x4*)src;
        f32x4 f1 = *(const f32x4*)(src+4);
        #pragma unroll
        for (int j=0;j<4;++j){ va[j]=bf16b(f0[j]); va[4+j]=bf16b(f1[j]); }
      } else {
        va = *(const short8*)(A + (size_t)(m0+row)*K + k0 + col);
      }
      *(short8*)((char*)As + byte) = va;
      const float* srcB = W + (size_t)(n0+row)*K + k0 + col;
      f32x4 g0 = *(const f32x4*)srcB;
      f32x4 g1 = *(const f32x4*)(srcB+4);
      short8 vb;
      #pragma unroll
      for (int j=0;j<4;++j){ vb[j]=bf16b(g0[j]); vb[4+j]=bf16b(g1[j]); }
      *(short8*)((char*)Bs + byte) = vb;
    }
    __syncthreads();
    short8 af[4], bfr[4];
    #pragma unroll
    for (int m=0;m<4;++m) {
      const int row = wr*64 + m*16 + l15;
      af[m] = *(const short8*)((const char*)As + row*64 + ((lg*16) ^ ((row&6)<<3)));
    }
    #pragma unroll
    for (int n=0;n<4;++n) {
      const int row = wc*64 + n*16 + l15;
      bfr[n] = *(const short8*)((const char*)Bs + row*64 + ((lg*16) ^ ((row&6)<<3)));
    }
    #pragma unroll
    for (int m=0;m<4;++m)
      #pragma unroll
      for (int n=0;n<4;++n)
        acc[m][n] = __builtin_amdgcn_mfma_f32_16x16x32_bf16(af[m], bfr[n], acc[m][n], 0, 0, 0);
    __syncthreads();
  }

  #pragma unroll
  for (int n=0;n<4;++n) {
    const int col = n0 + wc*64 + n*16 + l15;
    const float bv = bias[col];
    #pragma unroll
    for (int m=0;m<4;++m) {
      #pragma unroll
      for (int i=0;i<4;++i) {
        const int row = m0 + wr*64 + m*16 + lg*4 + i;
        const float val = (acc[m][n][i] + bv) * oscale;
        if constexpr (std::is_same<OT,float>::value) C[(size_t)row*N + col] = val;
        else                                         C[(size_t)row*N + col] = bf16b(val);
      }
    }
  }
}

// ---------------- V transpose: Vh[b*4096+s][h*64+dk] -> Vt[(b*16+h)*64+dk][s] ----
__global__ __launch_bounds__(256)
void transpose_v_kernel(const short* __restrict__ Vh, short* __restrict__ Vt)
{
  __shared__ short tile[64][65];
  const int t = threadIdx.x;
  const int bh = blockIdx.y, b = bh >> 4, h = bh & 15;
  const int s0 = blockIdx.x * 64;
  const int r = t >> 2;
  const int c = (t & 3) * 16;
  const short* src = Vh + (size_t)(b*4096 + s0 + r)*1024 + h*64 + c;
  short8 v0 = *(const short8*)src;
  short8 v1 = *(const short8*)(src + 8);
  #pragma unroll
  for (int j=0;j<8;++j){ tile[r][c+j]=v0[j]; tile[r][c+8+j]=v1[j]; }
  __syncthreads();
  short8 o0, o1;
  #pragma unroll
  for (int j=0;j<8;++j){ o0[j]=tile[c+j][r]; o1[j]=tile[c+8+j][r]; }
  short* dst = Vt + (size_t)(bh*64 + r)*4096 + s0 + c;
  *(short8*)dst = o0;
  *(short8*)(dst+8) = o1;
}

// ---------------- Flash attention, swapped-QK 32x32 structure ----------------
// Grid (32 q-blocks, 32 bh). 256 thr = 4 waves; wave owns 32 q-rows (QBLK=128).
// __launch_bounds__(256,3): 3 blocks/CU co-resident.
// Per lane: q = lane&31 for scores, l, m, AND O^T accumulator.
// P-exchange via permlane32_swap builtin (VALU) — LDS pipe was the binding pipe.
__global__ __launch_bounds__(256, 3)
void flash_kernel(const short* __restrict__ Qh, const short* __restrict__ Kh,
                  const short* __restrict__ Vt, const int* __restrict__ mask,
                  short* __restrict__ O)
{
  __shared__ __align__(16) char smem[49152];
  short* KsBuf = (short*)smem;               // [2][64*64] = 16KB
  short* VsBuf = (short*)(smem + 16384);     // [2][64*64] = 16KB
  float* MaskF = (float*)(smem + 32768);     // [4096]     = 16KB

  const int t = threadIdx.x;
  const int lane = t & 63, wv = t >> 6;
  const int l31 = lane & 31, hi = lane >> 5;
  const int rsw = (l31 & 7) << 4;
  const int bh = blockIdx.y, b = bh >> 4, h = bh & 15;
  const int q0 = blockIdx.x * 128;
  const bool lo = (lane < 32);

  // mask -> additive float (log2 domain), once per block
  for (int i = t; i < 4096; i += 256)
    MaskF[i] = (mask[b*4096 + i] == 0) ? -1.0e9f : 0.0f;

  // Q B-frags (already scaled by 0.125*log2e in the Q projection)
  short8 qf[4];
  {
    const short* qrow = Qh + (size_t)(b*4096 + q0 + wv*32 + l31)*1024 + h*64;
    #pragma unroll
    for (int ds=0; ds<4; ++ds)
      qf[ds] = *(const short8*)(qrow + ds*16 + hi*8);
  }

  float m_run = -3.0e38f;
  float l_run = 0.0f;
  f32x16 oA[2] = {};

  // prologue: stage tile 0 (256 threads: 2 K + 2 V short8 each)
  #pragma unroll
  for (int c = 0; c < 2; ++c) {
    const int e = t + c*256;
    const int row = e >> 3, sl = e & 7;
    const int byte = row*128 + ((sl*16) ^ ((row&7)<<4));
    *(short8*)((char*)KsBuf + byte) =
      *(const short8*)(Kh + (size_t)(b*4096 + row)*1024 + h*64 + sl*8);
    *(short8*)((char*)VsBuf + byte) =
      *(const short8*)(Vt + (size_t)(bh*64 + row)*4096 + sl*8);
  }
  __syncthreads();

  for (int kt = 0; kt < 64; ++kt) {
    const int cur = kt & 1;
    const char* KsC = (const char*)KsBuf + cur*8192;
    const char* VsC = (const char*)VsBuf + cur*8192;
    const bool more = (kt + 1 < 64);

    // issue next-tile global loads early (latency hides under QK+softmax+PV)
    short8 nk[2], nv[2];
    if (more) {
      #pragma unroll
      for (int c=0;c<2;++c){
        const int e = t + c*256; const int row = e>>3, sl = e&7;
        nk[c] = *(const short8*)(Kh + (size_t)(b*4096 + (kt+1)*64 + row)*1024 + h*64 + sl*8);
        nv[c] = *(const short8*)(Vt + (size_t)(bh*64 + row)*4096 + (kt+1)*64 + sl*8);
      }
    }

    // ---- S accumulator init = additive mask (keys per C-layout: (r&3)+8*(r>>2)+4*hi) ----
    f32x16 sA[2];
    #pragma unroll
    for (int kh=0;kh<2;++kh)
      #pragma unroll
      for (int rq=0;rq<4;++rq) {
        f32x4 mv = *(const f32x4*)(&MaskF[kt*64 + kh*32 + rq*8 + hi*4]);
        sA[kh][rq*4+0] = mv[0]; sA[kh][rq*4+1] = mv[1];
        sA[kh][rq*4+2] = mv[2]; sA[kh][rq*4+3] = mv[3];
      }

    // ---- S^T = K Q^T : lane holds q=l31, k over regs ----
    __builtin_amdgcn_s_setprio(1);
    #pragma unroll
    for (int ds=0; ds<4; ++ds) {
      short8 kf0 = *(const short8*)(KsC + l31*128       + ((ds*32 + hi*16) ^ rsw));
      short8 kf1 = *(const short8*)(KsC + (l31+32)*128  + ((ds*32 + hi*16) ^ rsw));
      sA[0] = __builtin_amdgcn_mfma_f32_32x32x16_bf16(kf0, qf[ds], sA[0], 0,0,0);
      sA[1] = __builtin_amdgcn_mfma_f32_32x32x16_bf16(kf1, qf[ds], sA[1], 0,0,0);
    }
    __builtin_amdgcn_s_setprio(0);

    // ---- online softmax (in-register, log2 domain) ----
    float mx[8];
    #pragma unroll
    for (int r=0;r<8;++r)
      mx[r] = fmaxf(fmaxf(sA[0][r], sA[0][r+8]), fmaxf(sA[1][r], sA[1][r+8]));
    #pragma unroll
    for (int s=4; s>0; s>>=1)
      #pragma unroll
      for (int r=0;r<4;++r) if (r < s) mx[r] = fmaxf(mx[r], mx[r+s]);
    float tmx = mx[0];
    {
      uint2v rr = plswap(__builtin_bit_cast(unsigned, tmx), __builtin_bit_cast(unsigned, tmx));
      const float cross = __builtin_bit_cast(float, lo ? rr[1] : rr[0]);
      tmx = fmaxf(tmx, cross);
    }

    // defer-max: only rescale when the running max grows materially (T13)
    if (!__all(tmx <= m_run + 8.0f)) {
      const float mnew = fmaxf(m_run, tmx);
      const float sc = exp2a(m_run - mnew);
      m_run = mnew;
      l_run *= sc;
      #pragma unroll
      for (int n=0;n<2;++n)
        #pragma unroll
        for (int r=0;r<16;++r) oA[n][r] *= sc;
    }

    f32x4 lp = {0.f,0.f,0.f,0.f};
    #pragma unroll
    for (int kh=0;kh<2;++kh)
      #pragma unroll
      for (int r=0;r<16;++r) {
        const float p = exp2a(sA[kh][r] - m_run);
        sA[kh][r] = p;
        lp[r&3] += p;
      }
    l_run += (lp[0]+lp[1]) + (lp[2]+lp[3]);

    // ---- P -> bf16 B-frags via cvt_pk + permlane32_swap builtin ----
    // target w[tt][w]: lane (q=l31,hi) holds keys (tt*16 + hi*8 + 2w, +1)
    // swap(c01,c45) = { [c01.lo|c45.lo], [c01.hi|c45.hi] } = (w0, w2)  [== R6 shfl mapping]
    unsigned w[4][4];
    #pragma unroll
    for (int tt=0; tt<4; ++tt) {
      const int kh = tt>>1, ro = (tt&1)*8;
      unsigned c01 = cvtpk(sA[kh][ro+0], sA[kh][ro+1]);
      unsigned c23 = cvtpk(sA[kh][ro+2], sA[kh][ro+3]);
      unsigned c45 = cvtpk(sA[kh][ro+4], sA[kh][ro+5]);
      unsigned c67 = cvtpk(sA[kh][ro+6], sA[kh][ro+7]);
      uint2v r02 = plswap(c01, c45);
      uint2v r13 = plswap(c23, c67);
      w[tt][0] = r02[0];   // keys hi*8+0,1
      w[tt][1] = r13[0];   // keys hi*8+2,3
      w[tt][2] = r02[1];   // keys hi*8+4,5
      w[tt][3] = r13[1];   // keys hi*8+6,7
    }

    // ---- O^T += V^T P^T ----
    __builtin_amdgcn_s_setprio(1);
    #pragma unroll
    for (int n=0;n<2;++n) {
      #pragma unroll
      for (int tt=0;tt<4;++tt) {
        short8 vf = *(const short8*)(VsC + (n*32+l31)*128 + ((tt*32 + hi*16) ^ rsw));
        uint4v wp = {w[tt][0], w[tt][1], w[tt][2], w[tt][3]};
        oA[n] = __builtin_amdgcn_mfma_f32_32x32x16_bf16(vf, __builtin_bit_cast(short8, wp), oA[n], 0,0,0);
      }
    }
    __builtin_amdgcn_s_setprio(0);

    // ---- write next tile into the other buffer ----
    if (more) {
      #pragma unroll
      for (int c=0;c<2;++c){
        const int e = t + c*256; const int row = e>>3, sl = e&7;
        const int byte = row*128 + ((sl*16) ^ ((row&7)<<4));
        *(short8*)((char*)KsBuf + (cur^1)*8192 + byte) = nk[c];
        *(short8*)((char*)VsBuf + (cur^1)*8192 + byte) = nv[c];
      }
    }
    __syncthreads();
  }

  // ---- epilogue ----
  {
    uint2v rl = plswap(__builtin_bit_cast(unsigned, l_run), __builtin_bit_cast(unsigned, l_run));
    l_run += __builtin_bit_cast(float, lo ? rl[1] : rl[0]);
  }
  const float inv = 1.0f / l_run;

  char* ot = smem + wv*4096;   // 4KB per wave (4 waves = 16KB)
  #pragma unroll
  for (int n=0;n<2;++n)
    #pragma unroll
    for (int rq=0;rq<4;++rq) {
      const unsigned w0 = cvtpk(oA[n][rq*4+0]*inv, oA[n][rq*4+1]*inv);
      const unsigned w1 = cvtpk(oA[n][rq*4+2]*inv, oA[n][rq*4+3]*inv);
      const int sl = n*4 + rq;
      const int byte = l31*128 + ((sl*16) ^ ((l31&7)<<4)) + hi*8;
      *(unsigned*)(ot + byte)     = w0;
      *(unsigned*)(ot + byte + 4) = w1;
    }
  asm volatile("s_waitcnt lgkmcnt(0)" ::: "memory");
  __builtin_amdgcn_sched_barrier(0);

  const int row = lane >> 1, half = lane & 1;
  const int orow = b*4096 + q0 + wv*32 + row;
  #pragma unroll
  for (int i=0;i<4;++i) {
    const int sl = half*4 + i;
    short8 vv = *(const short8*)(ot + row*128 + ((sl*16) ^ ((row&7)<<4)));
    *(short8*)(O + (size_t)orow*1024 + h*64 + half*32 + i*8) = vv;
  }
}

extern "C" void kernel_launch(void* const* d_in, const int* in_sizes, int n_in,
                              void* d_out, int out_size, void* d_ws, size_t ws_size,
                              hipStream_t stream)
{
  const float* q    = (const float*)d_in[0];
  const float* k    = (const float*)d_in[1];
  const float* v    = (const float*)d_in[2];
  const int*   mask = (const int*)d_in[3];
  const float* w_q  = (const float*)d_in[4];
  const float* b_q  = (const float*)d_in[5];
  const float* w_k  = (const float*)d_in[6];
  const float* b_k  = (const float*)d_in[7];
  const float* w_v  = (const float*)d_in[8];
  const float* b_v  = (const float*)d_in[9];
  const float* w_o  = (const float*)d_in[10];
  const float* b_o  = (const float*)d_in[11];
  float* out = (float*)d_out;

  char* ws = (char*)d_ws;
  const size_t SZ = (size_t)8192*1024*2;   // one bf16 [8192][1024] buffer
  short* QH = (short*)(ws);
  short* KH = (short*)(ws + SZ);
  short* OB = (short*)(ws + 2*SZ);         // V-proj output, then reused for attn out
  short* VT = (short*)(ws + 3*SZ);
  short* VH = OB;

  const float QSCALE = 0.125f * 1.44269504f;

  dim3 bG(256);
  dim3 gG(64, 8);
  hipLaunchKernelGGL((gemm_bt_kernel<float, short>), gG, bG, 0, stream, q, w_q, b_q, QH, 8192, 1024, 1024, QSCALE);
  hipLaunchKernelGGL((gemm_bt_kernel<float, short>), gG, bG, 0, stream, k, w_k, b_k, KH, 8192, 1024, 1024, 1.0f);
  hipLaunchKernelGGL((gemm_bt_kernel<float, short>), gG, bG, 0, stream, v, w_v, b_v, VH, 8192, 1024, 1024, 1.0f);
  hipLaunchKernelGGL(transpose_v_kernel, dim3(64, 32), bG, 0, stream, VH, VT);
  hipLaunchKernelGGL(flash_kernel, dim3(32, 32), dim3(256), 0, stream, QH, KH, VT, mask, OB);
  hipLaunchKernelGGL((gemm_bt_kernel<short, float>), gG, bG, 0, stream, OB, w_o, b_o, out, 8192, 1024, 1024, 1.0f);
}